// Round 3
// baseline (380.669 us; speedup 1.0000x reference)
//
#include <hip/hip_runtime.h>
#include <math.h>

// Soft-MoE forward, fp32. B=8, M=4096, D=512, E=64, P=1, H=2048.
// R3: gemm occupancy x2 + LDS-staged activations; gemm2 -> atomicAdd ys_f
// (ysred removed, zeroing folded into gelu, b2 folded into combine).

namespace {
constexpr int B = 8, M = 4096, D = 512, E = 64, H = 2048;
constexpr int NSD = 32;   // logits/dstat m-splits (128 rows each)
constexpr int NSX = 32;   // dispatch m-splits
constexpr int NK1 = 8;    // gemm1 d-splits

constexpr size_t OFF_INVN = 0;                            // B*M
constexpr size_t OFF_PHIN = OFF_INVN + (size_t)B * M;     // D*E
constexpr size_t OFF_LOG  = OFF_PHIN + (size_t)D * E;     // B*M*E
constexpr size_t OFF_PMAX = OFF_LOG  + (size_t)B * M * E; // B*NSD*E
constexpr size_t OFF_PSUM = OFF_PMAX + (size_t)B * NSD * E;
constexpr size_t OFF_XSP  = OFF_PSUM + (size_t)B * NSD * E; // NSX*B*E*D
constexpr size_t OFF_XSF  = OFF_XSP  + (size_t)NSX * B * E * D; // E*D*B
constexpr size_t OFF_HP   = OFF_XSF  + (size_t)E * D * B;   // NK1*E*H*B
constexpr size_t OFF_HT   = OFF_HP   + (size_t)NK1 * E * H * B; // E*H*B
constexpr size_t OFF_YSF  = OFF_HT   + (size_t)E * H * B;   // B*E*D
constexpr size_t WS_FLOATS = OFF_YSF + (size_t)E * D * B;   // ~82 MB
} // namespace

// ---- K2: phin = scale * l2norm(phi, axis=0). grid 64, block 256 ----
__global__ __launch_bounds__(256) void k_phinorm(const float* __restrict__ phi,
                                                 const float* __restrict__ scale,
                                                 float* __restrict__ phin) {
  int e = blockIdx.x;
  int t = threadIdx.x;
  float v0 = phi[(size_t)t * E + e];
  float v1 = phi[(size_t)(t + 256) * E + e];
  __shared__ float red[256];
  red[t] = v0 * v0 + v1 * v1;
  __syncthreads();
  for (int s = 128; s; s >>= 1) {
    if (t < s) red[t] += red[t + s];
    __syncthreads();
  }
  float inv = scale[0] / fmaxf(sqrtf(red[0]), 1e-12f);
  phin[(size_t)t * E + e]         = v0 * inv;
  phin[(size_t)(t + 256) * E + e] = v1 * inv;
}

// ---- K3: fused rownorm + logits + d-softmax partial stats ----
// grid 256 (128-row tiles), block 256; thread tile 8 rows x 4 e.
__global__ __launch_bounds__(256) void k_logits(const float* __restrict__ x,
                                                const float* __restrict__ phin,
                                                float* __restrict__ invn,
                                                float* __restrict__ logits,
                                                float* __restrict__ pmax,
                                                float* __restrict__ psum) {
  __shared__ float xT[16][132];
  __shared__ float ph[16][68];
  __shared__ float invs[128];
  __shared__ float sred[16][68];
  __shared__ float bmax[64];
  int t = threadIdx.x;
  int rowbase = blockIdx.x * 128;
  float acc[8][4];
#pragma unroll
  for (int i = 0; i < 8; i++)
#pragma unroll
    for (int j = 0; j < 4; j++) acc[i][j] = 0.f;
  int r0 = (t & 15) * 8;
  int e0 = (t >> 4) * 4;
  int srow = t >> 1;
  int sdh  = (t & 1) * 8;
  int pd = t >> 4;
  int pe = (t & 15) * 4;
  float ss = 0.f;
  for (int d0 = 0; d0 < D; d0 += 16) {
    __syncthreads();
    const float4* xp = (const float4*)(x + (size_t)(rowbase + srow) * D + d0 + sdh);
    float4 a = xp[0], b = xp[1];
    ss += a.x * a.x + a.y * a.y + a.z * a.z + a.w * a.w +
          b.x * b.x + b.y * b.y + b.z * b.z + b.w * b.w;
    xT[sdh + 0][srow] = a.x; xT[sdh + 1][srow] = a.y;
    xT[sdh + 2][srow] = a.z; xT[sdh + 3][srow] = a.w;
    xT[sdh + 4][srow] = b.x; xT[sdh + 5][srow] = b.y;
    xT[sdh + 6][srow] = b.z; xT[sdh + 7][srow] = b.w;
    *(float4*)&ph[pd][pe] = *(const float4*)(phin + (size_t)(d0 + pd) * E + pe);
    __syncthreads();
#pragma unroll 4
    for (int kk = 0; kk < 16; kk++) {
      float a8[8], b4[4];
      *(float4*)&a8[0] = *(float4*)&xT[kk][r0];
      *(float4*)&a8[4] = *(float4*)&xT[kk][r0 + 4];
      *(float4*)&b4[0] = *(float4*)&ph[kk][e0];
#pragma unroll
      for (int i = 0; i < 8; i++)
#pragma unroll
        for (int j = 0; j < 4; j++) acc[i][j] += a8[i] * b4[j];
    }
  }
  ss += __shfl_xor(ss, 1, 64);
  float iv = 1.0f / fmaxf(sqrtf(ss), 1e-12f);
  if ((t & 1) == 0) {
    invs[srow] = iv;
    invn[rowbase + srow] = iv;
  }
  __syncthreads();
#pragma unroll
  for (int i = 0; i < 8; i++) {
    float inv = invs[r0 + i];
#pragma unroll
    for (int j = 0; j < 4; j++) acc[i][j] *= inv;
    float4 o;
    o.x = acc[i][0]; o.y = acc[i][1]; o.z = acc[i][2]; o.w = acc[i][3];
    *(float4*)(logits + (size_t)(rowbase + r0 + i) * E + e0) = o;
  }
  int rg = t & 15;
#pragma unroll
  for (int j = 0; j < 4; j++) {
    float cm = acc[0][j];
#pragma unroll
    for (int i = 1; i < 8; i++) cm = fmaxf(cm, acc[i][j]);
    sred[rg][e0 + j] = cm;
  }
  __syncthreads();
  if (t < 64) {
    float g = sred[0][t];
#pragma unroll
    for (int i = 1; i < 16; i++) g = fmaxf(g, sred[i][t]);
    bmax[t] = g;
  }
  __syncthreads();
#pragma unroll
  for (int j = 0; j < 4; j++) {
    float bm = bmax[e0 + j];
    float s = 0.f;
#pragma unroll
    for (int i = 0; i < 8; i++) s += __expf(acc[i][j] - bm);
    sred[rg][e0 + j] = s;
  }
  __syncthreads();
  if (t < 64) {
    float s = 0.f;
#pragma unroll
    for (int i = 0; i < 16; i++) s += sred[i][t];
    pmax[(size_t)blockIdx.x * 64 + t] = bmax[t];
    psum[(size_t)blockIdx.x * 64 + t] = s;
  }
}

// ---- K5: dispatch partial: xs_part[ms][b][e][d] = sum_{m in split} exp(L-dmax)*xn ----
__global__ __launch_bounds__(256) void k_dispatch(const float* __restrict__ x,
                                                  const float* __restrict__ logits,
                                                  const float* __restrict__ invn,
                                                  const float* __restrict__ pmax,
                                                  float* __restrict__ xs_part) {
  __shared__ float wexp[32][68];
  __shared__ float xt[32][260];
  __shared__ float dmx[64];
  int t = threadIdx.x;
  int blk = blockIdx.x;
  int dg = blk & 1, ms = (blk >> 1) & 31, b = blk >> 6;
  int m0 = ms * 128;
  if (t < 64) {
    float g = pmax[((size_t)b * NSD) * 64 + t];
    for (int s = 1; s < NSD; s++)
      g = fmaxf(g, pmax[((size_t)(b * NSD + s)) * 64 + t]);
    dmx[t] = g;
  }
  float acc[8][8];
#pragma unroll
  for (int i = 0; i < 8; i++)
#pragma unroll
    for (int j = 0; j < 8; j++) acc[i][j] = 0.f;
  int e0 = (t & 7) * 8, d0 = (t >> 3) * 8;
  for (int c = 0; c < 4; c++) {
    int mr = m0 + c * 32;
    __syncthreads();
#pragma unroll
    for (int k = 0; k < 8; k++) {
      int idx = t + 256 * k;
      int r = idx >> 6, e = idx & 63;
      wexp[r][e] = __expf(logits[((size_t)(b * M + mr + r)) * E + e] - dmx[e]);
    }
#pragma unroll
    for (int k = 0; k < 8; k++) {
      int f4 = t + 256 * k;
      int r = f4 >> 6, ci = f4 & 63;
      float4 v = *(const float4*)(x + ((size_t)(b * M + mr + r)) * D + dg * 256 + ci * 4);
      float iv = invn[b * M + mr + r];
      v.x *= iv; v.y *= iv; v.z *= iv; v.w *= iv;
      *(float4*)&xt[r][ci * 4] = v;
    }
    __syncthreads();
#pragma unroll 2
    for (int r = 0; r < 32; r++) {
      float a8[8], x8[8];
      *(float4*)&a8[0] = *(float4*)&wexp[r][e0];
      *(float4*)&a8[4] = *(float4*)&wexp[r][e0 + 4];
      *(float4*)&x8[0] = *(float4*)&xt[r][d0];
      *(float4*)&x8[4] = *(float4*)&xt[r][d0 + 4];
#pragma unroll
      for (int i = 0; i < 8; i++)
#pragma unroll
        for (int j = 0; j < 8; j++) acc[i][j] += a8[i] * x8[j];
    }
  }
  float* outp = xs_part + ((size_t)ms * B + b) * E * D;
#pragma unroll
  for (int i = 0; i < 8; i++) {
    float* op = outp + (size_t)(e0 + i) * D + dg * 256 + d0;
    *(float4*)op       = *(float4*)&acc[i][0];
    *(float4*)(op + 4) = *(float4*)&acc[i][4];
  }
}

// ---- K5b: xs_f[e][d][b] = (sum_ms xs_part)/dsum, dsum inline. grid B*E=512 ----
__global__ __launch_bounds__(256) void k_xsred(const float* __restrict__ xs_part,
                                               const float* __restrict__ pmax,
                                               const float* __restrict__ psum,
                                               float* __restrict__ xs_f) {
  int blk = blockIdx.x;
  int b = blk >> 6, e = blk & 63;
  int t = threadIdx.x;
  float gm = -1e30f;
  for (int s = 0; s < NSD; s++)
    gm = fmaxf(gm, pmax[((size_t)(b * NSD + s)) * 64 + e]);
  float gs = 0.f;
  for (int s = 0; s < NSD; s++)
    gs += psum[((size_t)(b * NSD + s)) * 64 + e] *
          __expf(pmax[((size_t)(b * NSD + s)) * 64 + e] - gm);
  float inv = 1.0f / gs;
  const float2* pp = (const float2*)xs_part;
  size_t base = ((size_t)b * E + e) * (D / 2) + t;
  size_t slab = (size_t)B * E * (D / 2);
  float2 a = make_float2(0.f, 0.f);
  for (int ms = 0; ms < NSX; ms++) {
    float2 v = pp[(size_t)ms * slab + base];
    a.x += v.x; a.y += v.y;
  }
  int d = t * 2;
  xs_f[((size_t)e * D + d) * B + b]     = a.x * inv;
  xs_f[((size_t)e * D + d + 1) * B + b] = a.y * inv;
}

// ---- K6: h_part[ds][e][j][b] partial over 64-row d-slab. grid E*2*NK1=1024 ----
__global__ __launch_bounds__(256) void k_gemm1(const float* __restrict__ w1,
                                               const float* __restrict__ xs_f,
                                               float* __restrict__ h_part) {
  int blk = blockIdx.x;
  int ds = blk & 7, hs = (blk >> 3) & 1, e = blk >> 4;
  int t = threadIdx.x;
  __shared__ float xsm[64 * 8];  // xs slab [64 d][8 b]
  if (t < 128)
    ((float4*)xsm)[t] = ((const float4*)(xs_f + ((size_t)e * D + ds * 64) * B))[t];
  __syncthreads();
  int j0 = hs * 1024 + t * 4;
  const float* wp = w1 + ((size_t)e * D + ds * 64) * H + j0;
  float acc[4][8];
#pragma unroll
  for (int i = 0; i < 4; i++)
#pragma unroll
    for (int j = 0; j < 8; j++) acc[i][j] = 0.f;
#pragma unroll 8
  for (int d = 0; d < 64; d++) {
    float4 w = *(const float4*)(wp + (size_t)d * H);
    float x8[8];
    *(float4*)&x8[0] = *(float4*)&xsm[d * 8];
    *(float4*)&x8[4] = *(float4*)&xsm[d * 8 + 4];
#pragma unroll
    for (int bb = 0; bb < 8; bb++) {
      acc[0][bb] += w.x * x8[bb]; acc[1][bb] += w.y * x8[bb];
      acc[2][bb] += w.z * x8[bb]; acc[3][bb] += w.w * x8[bb];
    }
  }
  float* op = h_part + (((size_t)ds * E + e) * H + j0) * B;
#pragma unroll
  for (int i = 0; i < 4; i++) {
    *(float4*)(op + i * 8)     = *(float4*)&acc[i][0];
    *(float4*)(op + i * 8 + 4) = *(float4*)&acc[i][4];
  }
}

// ---- K6b: hT = gelu(sum_ds h_part + b1); blocks<64 also zero ys_f. grid 512 ----
__global__ __launch_bounds__(256) void k_gelu(const float* __restrict__ h_part,
                                              const float* __restrict__ b1,
                                              float* __restrict__ hT,
                                              float* __restrict__ ys_f) {
  int blk = blockIdx.x;
  int t = threadIdx.x;
  if (blk < 64) {
    float4 z = make_float4(0.f, 0.f, 0.f, 0.f);
#pragma unroll
    for (int k = 0; k < 4; k++)
      ((float4*)ys_f)[(size_t)blk * 1024 + k * 256 + t] = z;
  }
  int e = blk >> 3, jc = blk & 7;
  int j = jc * 256 + t;
  float a[8];
#pragma unroll
  for (int k = 0; k < 8; k++) a[k] = 0.f;
  const float* pp = h_part + ((size_t)e * H + j) * B;
  for (int ds = 0; ds < NK1; ds++) {
    const float* q = pp + (size_t)ds * E * H * B;
#pragma unroll
    for (int k = 0; k < 8; k++) a[k] += q[k];
  }
  float bias = b1[e * H + j];
  float* op = hT + ((size_t)e * H + j) * B;
#pragma unroll
  for (int k = 0; k < 8; k++) {
    float v = a[k] + bias;
    op[k] = 0.5f * v * (1.0f + erff(v * 0.70710678118654752f));
  }
}

// ---- K7: gemm2 partial over 128 k-rows -> atomicAdd ys_f[b][e][d]. grid E*16 ----
__global__ __launch_bounds__(256) void k_gemm2(const float* __restrict__ w2,
                                               const float* __restrict__ hT,
                                               float* __restrict__ ys_f) {
  int blk = blockIdx.x;
  int ks = blk & 15, e = blk >> 4;
  int t = threadIdx.x;
  __shared__ float hsm[128 * 8];  // hT slab [128 k][8 b]
  ((float4*)hsm)[t] = ((const float4*)(hT + ((size_t)e * H + ks * 128) * B))[t];
  __syncthreads();
  int kk = t >> 7, dq = t & 127;
  int d0 = dq * 4;
  const float* wp = w2 + ((size_t)e * H + ks * 128 + kk * 64) * D + d0;
  const float* hb = hsm + kk * 64 * 8;
  float acc[4][8];
#pragma unroll
  for (int i = 0; i < 4; i++)
#pragma unroll
    for (int j = 0; j < 8; j++) acc[i][j] = 0.f;
#pragma unroll 8
  for (int k = 0; k < 64; k++) {
    float4 w = *(const float4*)(wp + (size_t)k * D);
    float h8[8];
    *(float4*)&h8[0] = *(float4*)&hb[k * 8];
    *(float4*)&h8[4] = *(float4*)&hb[k * 8 + 4];
#pragma unroll
    for (int bb = 0; bb < 8; bb++) {
      acc[0][bb] += w.x * h8[bb]; acc[1][bb] += w.y * h8[bb];
      acc[2][bb] += w.z * h8[bb]; acc[3][bb] += w.w * h8[bb];
    }
  }
#pragma unroll
  for (int bb = 0; bb < 8; bb++) {
    float* yp = ys_f + ((size_t)bb * E + e) * D + d0;
#pragma unroll
    for (int i = 0; i < 4; i++) atomicAdd(yp + i, acc[i][bb]);
  }
}

// ---- K8: y[b][m][d] = sum_e softmax_e(L)[e] * (ys_f[b][e][d] + b2[e][d]) ----
__global__ __launch_bounds__(256) void k_combine(const float* __restrict__ logits,
                                                 const float* __restrict__ ys_f,
                                                 const float* __restrict__ b2,
                                                 float* __restrict__ y) {
  __shared__ float ysb[64][132];
  __shared__ float cT[64][68];
  __shared__ float red[64][4];
  __shared__ float gmx[64], gsm[64];
  int t = threadIdx.x;
  int blk = blockIdx.x;
  int dg = blk & 3, ms = (blk >> 2) & 31, b = blk >> 7;
  int m0 = ms * 128;
#pragma unroll
  for (int k = 0; k < 8; k++) {
    int f4 = t + 256 * k;
    int e = f4 >> 5, ci = f4 & 31;
    float4 v = *(const float4*)(ys_f + ((size_t)(b * E + e)) * D + dg * 128 + ci * 4);
    float4 bi = *(const float4*)(b2 + (size_t)e * D + dg * 128 + ci * 4);
    v.x += bi.x; v.y += bi.y; v.z += bi.z; v.w += bi.w;
    *(float4*)&ysb[e][ci * 4] = v;
  }
  int r0 = (t & 7) * 8;
  int d0 = (t >> 3) * 4;
  int row = t >> 2;
  int sub = t & 3;
  for (int ch = 0; ch < 2; ch++) {
    int mr = m0 + ch * 64;
    float r16[16];
    const float* Lr = logits + ((size_t)(b * M + mr + row)) * E + sub * 16;
#pragma unroll
    for (int k = 0; k < 4; k++) *(float4*)&r16[k * 4] = *(const float4*)(Lr + k * 4);
    float lm = -1e30f;
#pragma unroll
    for (int k = 0; k < 16; k++) lm = fmaxf(lm, r16[k]);
    __syncthreads();
    red[row][sub] = lm;
    __syncthreads();
    if (sub == 0) {
      float g = fmaxf(fmaxf(red[row][0], red[row][1]), fmaxf(red[row][2], red[row][3]));
      gmx[row] = g;
    }
    __syncthreads();
    float g = gmx[row];
    float ls = 0.f;
#pragma unroll
    for (int k = 0; k < 16; k++) {
      r16[k] = __expf(r16[k] - g);
      ls += r16[k];
    }
    __syncthreads();
    red[row][sub] = ls;
    __syncthreads();
    if (sub == 0)
      gsm[row] = 1.0f / (red[row][0] + red[row][1] + red[row][2] + red[row][3]);
    __syncthreads();
    float is = gsm[row];
#pragma unroll
    for (int k = 0; k < 16; k++) cT[sub * 16 + k][row] = r16[k] * is;
    __syncthreads();
    float acc[8][4];
#pragma unroll
    for (int i = 0; i < 8; i++)
#pragma unroll
      for (int j = 0; j < 4; j++) acc[i][j] = 0.f;
#pragma unroll 4
    for (int e = 0; e < 64; e++) {
      float c8[8], y4[4];
      *(float4*)&c8[0] = *(float4*)&cT[e][r0];
      *(float4*)&c8[4] = *(float4*)&cT[e][r0 + 4];
      *(float4*)&y4[0] = *(float4*)&ysb[e][d0];
#pragma unroll
      for (int i = 0; i < 8; i++)
#pragma unroll
        for (int j = 0; j < 4; j++) acc[i][j] += c8[i] * y4[j];
    }
#pragma unroll
    for (int i = 0; i < 8; i++) {
      float* op = y + ((size_t)(b * M + mr + r0 + i)) * D + dg * 128 + d0;
      *(float4*)op = *(float4*)&acc[i][0];
    }
  }
}

extern "C" void kernel_launch(void* const* d_in, const int* in_sizes, int n_in,
                              void* d_out, int out_size, void* d_ws, size_t ws_size,
                              hipStream_t stream) {
  const float* x     = (const float*)d_in[0];
  const float* phi   = (const float*)d_in[1];
  const float* scale = (const float*)d_in[2];
  const float* w1    = (const float*)d_in[3];
  const float* b1    = (const float*)d_in[4];
  const float* w2    = (const float*)d_in[5];
  const float* b2    = (const float*)d_in[6];
  float* y = (float*)d_out;
  float* ws = (float*)d_ws;
  (void)in_sizes; (void)n_in; (void)out_size; (void)ws_size;

  float* invn    = ws + OFF_INVN;
  float* phin    = ws + OFF_PHIN;
  float* logits  = ws + OFF_LOG;
  float* pmax    = ws + OFF_PMAX;
  float* psum    = ws + OFF_PSUM;
  float* xs_part = ws + OFF_XSP;
  float* xs_f    = ws + OFF_XSF;
  float* h_part  = ws + OFF_HP;
  float* hT      = ws + OFF_HT;
  float* ys_f    = ws + OFF_YSF;

  k_phinorm<<<E, 256, 0, stream>>>(phi, scale, phin);
  k_logits<<<(B * M) / 128, 256, 0, stream>>>(x, phin, invn, logits, pmax, psum);
  k_dispatch<<<B * NSX * 2, 256, 0, stream>>>(x, logits, invn, pmax, xs_part);
  k_xsred<<<B * E, 256, 0, stream>>>(xs_part, pmax, psum, xs_f);
  k_gemm1<<<E * 2 * NK1, 256, 0, stream>>>(w1, xs_f, h_part);
  k_gelu<<<E * 8, 256, 0, stream>>>(h_part, b1, hT, ys_f);
  k_gemm2<<<E * 16, 256, 0, stream>>>(w2, hT, ys_f);
  k_combine<<<B * 32 * 4, 256, 0, stream>>>(logits, ys_f, b2, y);
}

// Round 4
// 258.506 us; speedup vs baseline: 1.4726x; 1.4726x over previous
//
#include <hip/hip_runtime.h>
#include <hip/hip_bf16.h>
#include <math.h>

// Soft-MoE forward. B=8, M=4096, D=512, E=64, P=1, H=2048.
// R4: gemm2 reverted to slab-partials (atomics removed); logits rewritten
// with bf16 MFMA (operands bf16, fp32 accum; phin stored bf16 [e][d]).

namespace {
constexpr int B = 8, M = 4096, D = 512, E = 64, H = 2048;
constexpr int NSD = 32;   // logits/dstat m-splits (128 rows each)
constexpr int NSX = 32;   // dispatch m-splits
constexpr int NK1 = 8;    // gemm1 d-splits
constexpr int NK2 = 16;   // gemm2 k-slabs

constexpr size_t OFF_INVN = 0;                            // B*M
constexpr size_t OFF_PHIN = OFF_INVN + (size_t)B * M;     // D*E (bf16 in float slot)
constexpr size_t OFF_LOG  = OFF_PHIN + (size_t)D * E;     // B*M*E
constexpr size_t OFF_PMAX = OFF_LOG  + (size_t)B * M * E; // B*NSD*E
constexpr size_t OFF_PSUM = OFF_PMAX + (size_t)B * NSD * E;
constexpr size_t OFF_XSP  = OFF_PSUM + (size_t)B * NSD * E; // NSX*B*E*D
constexpr size_t OFF_XSF  = OFF_XSP  + (size_t)NSX * B * E * D; // E*D*B
constexpr size_t OFF_HP   = OFF_XSF  + (size_t)E * D * B;   // NK1*E*H*B
constexpr size_t OFF_HT   = OFF_HP   + (size_t)NK1 * E * H * B; // E*H*B
constexpr size_t OFF_YSP  = OFF_HT   + (size_t)E * H * B;   // NK2*E*D*B
constexpr size_t OFF_YSF  = OFF_YSP  + (size_t)NK2 * E * D * B; // B*E*D
constexpr size_t WS_FLOATS = OFF_YSF + (size_t)E * D * B;   // ~99 MB
} // namespace

typedef __attribute__((ext_vector_type(8))) short short8v;
typedef __attribute__((ext_vector_type(4))) float f32x4;

static __device__ inline unsigned short f2bf(float f) {
  __hip_bfloat16 h = __float2bfloat16(f);
  return *reinterpret_cast<unsigned short*>(&h);
}

// ---- K2: phT[e][d] = bf16(scale * l2norm(phi, axis=0)). grid 64, block 256 ----
__global__ __launch_bounds__(256) void k_phinorm(const float* __restrict__ phi,
                                                 const float* __restrict__ scale,
                                                 unsigned short* __restrict__ phT) {
  int e = blockIdx.x;
  int t = threadIdx.x;
  float v0 = phi[(size_t)t * E + e];
  float v1 = phi[(size_t)(t + 256) * E + e];
  __shared__ float red[256];
  red[t] = v0 * v0 + v1 * v1;
  __syncthreads();
  for (int s = 128; s; s >>= 1) {
    if (t < s) red[t] += red[t + s];
    __syncthreads();
  }
  float inv = scale[0] / fmaxf(sqrtf(red[0]), 1e-12f);
  phT[(size_t)e * D + t]       = f2bf(v0 * inv);
  phT[(size_t)e * D + t + 256] = f2bf(v1 * inv);
}

// ---- K3: fused rownorm + logits (bf16 MFMA) + d-softmax partial stats ----
// grid 256 (128-row tiles), block 256 = 4 waves; wave w owns rows w*32..w*32+31.
__global__ __launch_bounds__(256) void k_logits(const float* __restrict__ x,
                                                const unsigned short* __restrict__ phT,
                                                float* __restrict__ invn,
                                                float* __restrict__ logits,
                                                float* __restrict__ pmax,
                                                float* __restrict__ psum) {
  __shared__ __align__(16) unsigned short phs[64 * 520];  // [e][k] pad 520
  __shared__ __align__(16) unsigned short xA[128 * 56];   // [row][k] pad 56
  __shared__ float invs[128];
  __shared__ float smax[4][64];
  __shared__ float bmax[64];
  int t = threadIdx.x;
  int lane = t & 63, w = t >> 6;
  int rowbase = blockIdx.x * 128;
  // stage full phin-bf16 [64][512] -> LDS (row stride 520)
  {
    int e = t >> 2, q0 = (t & 3) * 16;
#pragma unroll
    for (int q = 0; q < 16; q++)
      *(short8v*)&phs[e * 520 + (q0 + q) * 8] =
          *(const short8v*)&phT[(size_t)e * D + (q0 + q) * 8];
  }
  int srow = t >> 1;        // 0..127
  int kb = (t & 1) * 16;    // k sub-offset within 32-chunk
  float ss = 0.f;
  f32x4 acc[2][4];
#pragma unroll
  for (int i = 0; i < 2; i++)
#pragma unroll
    for (int j = 0; j < 4; j++) acc[i][j] = (f32x4)(0.f);
  int kg = lane >> 4;       // 0..3 (k-group of 8)
  int l15 = lane & 15;
  for (int ks = 0; ks < 16; ks++) {
    __syncthreads();
    const float4* xp = (const float4*)(x + (size_t)(rowbase + srow) * D + ks * 32 + kb);
#pragma unroll
    for (int q = 0; q < 4; q++) {
      float4 v = xp[q];
      ss += v.x * v.x + v.y * v.y + v.z * v.z + v.w * v.w;
      ushort4 u;
      u.x = f2bf(v.x); u.y = f2bf(v.y); u.z = f2bf(v.z); u.w = f2bf(v.w);
      *(ushort4*)&xA[srow * 56 + kb + q * 4] = u;
    }
    __syncthreads();
    short8v a0 = *(short8v*)&xA[(w * 32 + l15) * 56 + kg * 8];
    short8v a1 = *(short8v*)&xA[(w * 32 + 16 + l15) * 56 + kg * 8];
    short8v b0 = *(short8v*)&phs[(l15)      * 520 + ks * 32 + kg * 8];
    short8v b1 = *(short8v*)&phs[(16 + l15) * 520 + ks * 32 + kg * 8];
    short8v b2 = *(short8v*)&phs[(32 + l15) * 520 + ks * 32 + kg * 8];
    short8v b3 = *(short8v*)&phs[(48 + l15) * 520 + ks * 32 + kg * 8];
    acc[0][0] = __builtin_amdgcn_mfma_f32_16x16x32_bf16(a0, b0, acc[0][0], 0, 0, 0);
    acc[0][1] = __builtin_amdgcn_mfma_f32_16x16x32_bf16(a0, b1, acc[0][1], 0, 0, 0);
    acc[0][2] = __builtin_amdgcn_mfma_f32_16x16x32_bf16(a0, b2, acc[0][2], 0, 0, 0);
    acc[0][3] = __builtin_amdgcn_mfma_f32_16x16x32_bf16(a0, b3, acc[0][3], 0, 0, 0);
    acc[1][0] = __builtin_amdgcn_mfma_f32_16x16x32_bf16(a1, b0, acc[1][0], 0, 0, 0);
    acc[1][1] = __builtin_amdgcn_mfma_f32_16x16x32_bf16(a1, b1, acc[1][1], 0, 0, 0);
    acc[1][2] = __builtin_amdgcn_mfma_f32_16x16x32_bf16(a1, b2, acc[1][2], 0, 0, 0);
    acc[1][3] = __builtin_amdgcn_mfma_f32_16x16x32_bf16(a1, b3, acc[1][3], 0, 0, 0);
  }
  // row norms: pair (t, t^1) covers a full row
  ss += __shfl_xor(ss, 1, 64);
  float iv = 1.0f / fmaxf(sqrtf(ss), 1e-12f);
  if ((t & 1) == 0) {
    invs[srow] = iv;
    invn[rowbase + srow] = iv;
  }
  __syncthreads();
  // scale by invn, write logits, track per-e max
  float lm[4] = {-1e30f, -1e30f, -1e30f, -1e30f};
  int rsub = (lane >> 4) * 4;  // D-frag row offset
#pragma unroll
  for (int fi = 0; fi < 2; fi++)
#pragma unroll
    for (int r = 0; r < 4; r++) {
      int row = w * 32 + fi * 16 + rsub + r;
      float ivr = invs[row];
#pragma unroll
      for (int eg = 0; eg < 4; eg++) {
        float v = acc[fi][eg][r] * ivr;
        logits[(size_t)(rowbase + row) * E + eg * 16 + l15] = v;
        lm[eg] = fmaxf(lm[eg], v);
      }
    }
#pragma unroll
  for (int eg = 0; eg < 4; eg++) {
    lm[eg] = fmaxf(lm[eg], __shfl_xor(lm[eg], 16, 64));
    lm[eg] = fmaxf(lm[eg], __shfl_xor(lm[eg], 32, 64));
  }
  if (lane < 16)
#pragma unroll
    for (int eg = 0; eg < 4; eg++) smax[w][eg * 16 + lane] = lm[eg];
  __syncthreads();
  if (t < 64)
    bmax[t] = fmaxf(fmaxf(smax[0][t], smax[1][t]), fmaxf(smax[2][t], smax[3][t]));
  __syncthreads();
  float ps[4] = {0.f, 0.f, 0.f, 0.f};
#pragma unroll
  for (int fi = 0; fi < 2; fi++)
#pragma unroll
    for (int r = 0; r < 4; r++) {
      int row = w * 32 + fi * 16 + rsub + r;
      float ivr = invs[row];
#pragma unroll
      for (int eg = 0; eg < 4; eg++)
        ps[eg] += __expf(acc[fi][eg][r] * ivr - bmax[eg * 16 + l15]);
    }
#pragma unroll
  for (int eg = 0; eg < 4; eg++) {
    ps[eg] += __shfl_xor(ps[eg], 16, 64);
    ps[eg] += __shfl_xor(ps[eg], 32, 64);
  }
  __syncthreads();  // all waves done reading bmax/smax
  if (lane < 16)
#pragma unroll
    for (int eg = 0; eg < 4; eg++) smax[w][eg * 16 + lane] = ps[eg];
  __syncthreads();
  if (t < 64) {
    pmax[(size_t)blockIdx.x * 64 + t] = bmax[t];
    psum[(size_t)blockIdx.x * 64 + t] =
        smax[0][t] + smax[1][t] + smax[2][t] + smax[3][t];
  }
}

// ---- K5: dispatch partial: xs_part[ms][b][e][d] = sum_{m in split} exp(L-dmax)*xn ----
__global__ __launch_bounds__(256) void k_dispatch(const float* __restrict__ x,
                                                  const float* __restrict__ logits,
                                                  const float* __restrict__ invn,
                                                  const float* __restrict__ pmax,
                                                  float* __restrict__ xs_part) {
  __shared__ float wexp[32][68];
  __shared__ float xt[32][260];
  __shared__ float dmx[64];
  int t = threadIdx.x;
  int blk = blockIdx.x;
  int dg = blk & 1, ms = (blk >> 1) & 31, b = blk >> 6;
  int m0 = ms * 128;
  if (t < 64) {
    float g = pmax[((size_t)b * NSD) * 64 + t];
    for (int s = 1; s < NSD; s++)
      g = fmaxf(g, pmax[((size_t)(b * NSD + s)) * 64 + t]);
    dmx[t] = g;
  }
  float acc[8][8];
#pragma unroll
  for (int i = 0; i < 8; i++)
#pragma unroll
    for (int j = 0; j < 8; j++) acc[i][j] = 0.f;
  int e0 = (t & 7) * 8, d0 = (t >> 3) * 8;
  for (int c = 0; c < 4; c++) {
    int mr = m0 + c * 32;
    __syncthreads();
#pragma unroll
    for (int k = 0; k < 8; k++) {
      int idx = t + 256 * k;
      int r = idx >> 6, e = idx & 63;
      wexp[r][e] = __expf(logits[((size_t)(b * M + mr + r)) * E + e] - dmx[e]);
    }
#pragma unroll
    for (int k = 0; k < 8; k++) {
      int f4 = t + 256 * k;
      int r = f4 >> 6, ci = f4 & 63;
      float4 v = *(const float4*)(x + ((size_t)(b * M + mr + r)) * D + dg * 256 + ci * 4);
      float iv = invn[b * M + mr + r];
      v.x *= iv; v.y *= iv; v.z *= iv; v.w *= iv;
      *(float4*)&xt[r][ci * 4] = v;
    }
    __syncthreads();
#pragma unroll 2
    for (int r = 0; r < 32; r++) {
      float a8[8], x8[8];
      *(float4*)&a8[0] = *(float4*)&wexp[r][e0];
      *(float4*)&a8[4] = *(float4*)&wexp[r][e0 + 4];
      *(float4*)&x8[0] = *(float4*)&xt[r][d0];
      *(float4*)&x8[4] = *(float4*)&xt[r][d0 + 4];
#pragma unroll
      for (int i = 0; i < 8; i++)
#pragma unroll
        for (int j = 0; j < 8; j++) acc[i][j] += a8[i] * x8[j];
    }
  }
  float* outp = xs_part + ((size_t)ms * B + b) * E * D;
#pragma unroll
  for (int i = 0; i < 8; i++) {
    float* op = outp + (size_t)(e0 + i) * D + dg * 256 + d0;
    *(float4*)op       = *(float4*)&acc[i][0];
    *(float4*)(op + 4) = *(float4*)&acc[i][4];
  }
}

// ---- K5b: xs_f[e][d][b] = (sum_ms xs_part)/dsum, dsum inline. grid B*E=512 ----
__global__ __launch_bounds__(256) void k_xsred(const float* __restrict__ xs_part,
                                               const float* __restrict__ pmax,
                                               const float* __restrict__ psum,
                                               float* __restrict__ xs_f) {
  int blk = blockIdx.x;
  int b = blk >> 6, e = blk & 63;
  int t = threadIdx.x;
  float gm = -1e30f;
  for (int s = 0; s < NSD; s++)
    gm = fmaxf(gm, pmax[((size_t)(b * NSD + s)) * 64 + e]);
  float gs = 0.f;
  for (int s = 0; s < NSD; s++)
    gs += psum[((size_t)(b * NSD + s)) * 64 + e] *
          __expf(pmax[((size_t)(b * NSD + s)) * 64 + e] - gm);
  float inv = 1.0f / gs;
  const float2* pp = (const float2*)xs_part;
  size_t base = ((size_t)b * E + e) * (D / 2) + t;
  size_t slab = (size_t)B * E * (D / 2);
  float2 a = make_float2(0.f, 0.f);
  for (int ms = 0; ms < NSX; ms++) {
    float2 v = pp[(size_t)ms * slab + base];
    a.x += v.x; a.y += v.y;
  }
  int d = t * 2;
  xs_f[((size_t)e * D + d) * B + b]     = a.x * inv;
  xs_f[((size_t)e * D + d + 1) * B + b] = a.y * inv;
}

// ---- K6: h_part[ds][e][j][b] partial over 64-row d-slab. grid E*2*NK1=1024 ----
__global__ __launch_bounds__(256) void k_gemm1(const float* __restrict__ w1,
                                               const float* __restrict__ xs_f,
                                               float* __restrict__ h_part) {
  int blk = blockIdx.x;
  int ds = blk & 7, hs = (blk >> 3) & 1, e = blk >> 4;
  int t = threadIdx.x;
  __shared__ float xsm[64 * 8];  // xs slab [64 d][8 b]
  if (t < 128)
    ((float4*)xsm)[t] = ((const float4*)(xs_f + ((size_t)e * D + ds * 64) * B))[t];
  __syncthreads();
  int j0 = hs * 1024 + t * 4;
  const float* wp = w1 + ((size_t)e * D + ds * 64) * H + j0;
  float acc[4][8];
#pragma unroll
  for (int i = 0; i < 4; i++)
#pragma unroll
    for (int j = 0; j < 8; j++) acc[i][j] = 0.f;
#pragma unroll 8
  for (int d = 0; d < 64; d++) {
    float4 w = *(const float4*)(wp + (size_t)d * H);
    float x8[8];
    *(float4*)&x8[0] = *(float4*)&xsm[d * 8];
    *(float4*)&x8[4] = *(float4*)&xsm[d * 8 + 4];
#pragma unroll
    for (int bb = 0; bb < 8; bb++) {
      acc[0][bb] += w.x * x8[bb]; acc[1][bb] += w.y * x8[bb];
      acc[2][bb] += w.z * x8[bb]; acc[3][bb] += w.w * x8[bb];
    }
  }
  float* op = h_part + (((size_t)ds * E + e) * H + j0) * B;
#pragma unroll
  for (int i = 0; i < 4; i++) {
    *(float4*)(op + i * 8)     = *(float4*)&acc[i][0];
    *(float4*)(op + i * 8 + 4) = *(float4*)&acc[i][4];
  }
}

// ---- K6b: hT[e][j][b] = gelu(sum_ds h_part + b1). grid E*8=512, block 256 ----
__global__ __launch_bounds__(256) void k_gelu(const float* __restrict__ h_part,
                                              const float* __restrict__ b1,
                                              float* __restrict__ hT) {
  int blk = blockIdx.x;
  int e = blk >> 3, jc = blk & 7;
  int t = threadIdx.x;
  int j = jc * 256 + t;
  float a[8];
#pragma unroll
  for (int k = 0; k < 8; k++) a[k] = 0.f;
  const float* pp = h_part + ((size_t)e * H + j) * B;
  for (int ds = 0; ds < NK1; ds++) {
    const float* q = pp + (size_t)ds * E * H * B;
#pragma unroll
    for (int k = 0; k < 8; k++) a[k] += q[k];
  }
  float bias = b1[e * H + j];
  float* op = hT + ((size_t)e * H + j) * B;
#pragma unroll
  for (int k = 0; k < 8; k++) {
    float v = a[k] + bias;
    op[k] = 0.5f * v * (1.0f + erff(v * 0.70710678118654752f));
  }
}

// ---- K7: gemm2 slab partial (128 k-rows, kk halves combined in LDS).
// grid E*16=1024, block 256; writes ys_part[ks][e][d][b].
__global__ __launch_bounds__(256) void k_gemm2(const float* __restrict__ w2,
                                               const float* __restrict__ hT,
                                               float* __restrict__ ys_part) {
  int blk = blockIdx.x;
  int ks = blk & 15, e = blk >> 4;
  int t = threadIdx.x;
  __shared__ float hsm[128 * 8];   // hT slab [128 k][8 b]
  __shared__ float rbuf[128 * 32]; // kk=1 partials
  ((float4*)hsm)[t] = ((const float4*)(hT + ((size_t)e * H + ks * 128) * B))[t];
  __syncthreads();
  int kk = t >> 7, dq = t & 127;
  int d0 = dq * 4;
  const float* wp = w2 + ((size_t)e * H + ks * 128 + kk * 64) * D + d0;
  const float* hb = hsm + kk * 64 * 8;
  float acc[4][8];
#pragma unroll
  for (int i = 0; i < 4; i++)
#pragma unroll
    for (int j = 0; j < 8; j++) acc[i][j] = 0.f;
#pragma unroll 8
  for (int k = 0; k < 64; k++) {
    float4 w = *(const float4*)(wp + (size_t)k * D);
    float h8[8];
    *(float4*)&h8[0] = *(float4*)&hb[k * 8];
    *(float4*)&h8[4] = *(float4*)&hb[k * 8 + 4];
#pragma unroll
    for (int bb = 0; bb < 8; bb++) {
      acc[0][bb] += w.x * h8[bb]; acc[1][bb] += w.y * h8[bb];
      acc[2][bb] += w.z * h8[bb]; acc[3][bb] += w.w * h8[bb];
    }
  }
  if (kk) {
#pragma unroll
    for (int i = 0; i < 4; i++) {
      *(float4*)&rbuf[dq * 32 + i * 8]     = *(float4*)&acc[i][0];
      *(float4*)&rbuf[dq * 32 + i * 8 + 4] = *(float4*)&acc[i][4];
    }
  }
  __syncthreads();
  if (!kk) {
    float* op = ys_part + (((size_t)ks * E + e) * D + d0) * B;
#pragma unroll
    for (int i = 0; i < 4; i++) {
      float4 r0 = *(float4*)&rbuf[dq * 32 + i * 8];
      float4 r1 = *(float4*)&rbuf[dq * 32 + i * 8 + 4];
      float4 o0, o1;
      o0.x = acc[i][0] + r0.x; o0.y = acc[i][1] + r0.y;
      o0.z = acc[i][2] + r0.z; o0.w = acc[i][3] + r0.w;
      o1.x = acc[i][4] + r1.x; o1.y = acc[i][5] + r1.y;
      o1.z = acc[i][6] + r1.z; o1.w = acc[i][7] + r1.w;
      *(float4*)(op + i * 8)     = o0;
      *(float4*)(op + i * 8 + 4) = o1;
    }
  }
}

// ---- K7b: ys_f[b][e][d] = sum_ks ys_part (b2 added in combine). grid E*4 ----
__global__ __launch_bounds__(256) void k_ysred(const float* __restrict__ ys_part,
                                               float* __restrict__ ys_f) {
  int e = blockIdx.x >> 2, kq = blockIdx.x & 3;
  int t = threadIdx.x;
  int i4 = kq * 256 + t;  // float4 index within [512 d][8 b] slab
  float4 a = make_float4(0.f, 0.f, 0.f, 0.f);
  for (int ks = 0; ks < NK2; ks++) {
    const float4* q = (const float4*)(ys_part + ((size_t)ks * E + e) * D * B);
    float4 v = q[i4];
    a.x += v.x; a.y += v.y; a.z += v.z; a.w += v.w;
  }
  int d = i4 >> 1, bh = (i4 & 1) * 4;
  ys_f[((size_t)(bh + 0) * E + e) * D + d] = a.x;
  ys_f[((size_t)(bh + 1) * E + e) * D + d] = a.y;
  ys_f[((size_t)(bh + 2) * E + e) * D + d] = a.z;
  ys_f[((size_t)(bh + 3) * E + e) * D + d] = a.w;
}

// ---- K8: y[b][m][d] = sum_e softmax_e(L)[e] * (ys_f[b][e][d] + b2[e][d]) ----
__global__ __launch_bounds__(256) void k_combine(const float* __restrict__ logits,
                                                 const float* __restrict__ ys_f,
                                                 const float* __restrict__ b2,
                                                 float* __restrict__ y) {
  __shared__ float ysb[64][132];
  __shared__ float cT[64][68];
  __shared__ float red[64][4];
  __shared__ float gmx[64], gsm[64];
  int t = threadIdx.x;
  int blk = blockIdx.x;
  int dg = blk & 3, ms = (blk >> 2) & 31, b = blk >> 7;
  int m0 = ms * 128;
#pragma unroll
  for (int k = 0; k < 8; k++) {
    int f4 = t + 256 * k;
    int e = f4 >> 5, ci = f4 & 31;
    float4 v = *(const float4*)(ys_f + ((size_t)(b * E + e)) * D + dg * 128 + ci * 4);
    float4 bi = *(const float4*)(b2 + (size_t)e * D + dg * 128 + ci * 4);
    v.x += bi.x; v.y += bi.y; v.z += bi.z; v.w += bi.w;
    *(float4*)&ysb[e][ci * 4] = v;
  }
  int r0 = (t & 7) * 8;
  int d0 = (t >> 3) * 4;
  int row = t >> 2;
  int sub = t & 3;
  for (int ch = 0; ch < 2; ch++) {
    int mr = m0 + ch * 64;
    float r16[16];
    const float* Lr = logits + ((size_t)(b * M + mr + row)) * E + sub * 16;
#pragma unroll
    for (int k = 0; k < 4; k++) *(float4*)&r16[k * 4] = *(const float4*)(Lr + k * 4);
    float lm = -1e30f;
#pragma unroll
    for (int k = 0; k < 16; k++) lm = fmaxf(lm, r16[k]);
    __syncthreads();
    red[row][sub] = lm;
    __syncthreads();
    if (sub == 0) {
      float g = fmaxf(fmaxf(red[row][0], red[row][1]), fmaxf(red[row][2], red[row][3]));
      gmx[row] = g;
    }
    __syncthreads();
    float g = gmx[row];
    float ls = 0.f;
#pragma unroll
    for (int k = 0; k < 16; k++) {
      r16[k] = __expf(r16[k] - g);
      ls += r16[k];
    }
    __syncthreads();
    red[row][sub] = ls;
    __syncthreads();
    if (sub == 0)
      gsm[row] = 1.0f / (red[row][0] + red[row][1] + red[row][2] + red[row][3]);
    __syncthreads();
    float is = gsm[row];
#pragma unroll
    for (int k = 0; k < 16; k++) cT[sub * 16 + k][row] = r16[k] * is;
    __syncthreads();
    float acc[8][4];
#pragma unroll
    for (int i = 0; i < 8; i++)
#pragma unroll
      for (int j = 0; j < 4; j++) acc[i][j] = 0.f;
#pragma unroll 4
    for (int e = 0; e < 64; e++) {
      float c8[8], y4[4];
      *(float4*)&c8[0] = *(float4*)&cT[e][r0];
      *(float4*)&c8[4] = *(float4*)&cT[e][r0 + 4];
      *(float4*)&y4[0] = *(float4*)&ysb[e][d0];
#pragma unroll
      for (int i = 0; i < 8; i++)
#pragma unroll
        for (int j = 0; j < 4; j++) acc[i][j] += c8[i] * y4[j];
    }
#pragma unroll
    for (int i = 0; i < 8; i++) {
      float* op = y + ((size_t)(b * M + mr + r0 + i)) * D + dg * 128 + d0;
      *(float4*)op = *(float4*)&acc[i][0];
    }
  }
}

extern "C" void kernel_launch(void* const* d_in, const int* in_sizes, int n_in,
                              void* d_out, int out_size, void* d_ws, size_t ws_size,
                              hipStream_t stream) {
  const float* x     = (const float*)d_in[0];
  const float* phi   = (const float*)d_in[1];
  const float* scale = (const float*)d_in[2];
  const float* w1    = (const float*)d_in[3];
  const float* b1    = (const float*)d_in[4];
  const float* w2    = (const float*)d_in[5];
  const float* b2    = (const float*)d_in[6];
  float* y = (float*)d_out;
  float* ws = (float*)d_ws;
  (void)in_sizes; (void)n_in; (void)out_size; (void)ws_size;

  float* invn           = ws + OFF_INVN;
  unsigned short* phT   = (unsigned short*)(ws + OFF_PHIN);
  float* logits  = ws + OFF_LOG;
  float* pmax    = ws + OFF_PMAX;
  float* psum    = ws + OFF_PSUM;
  float* xs_part = ws + OFF_XSP;
  float* xs_f    = ws + OFF_XSF;
  float* h_part  = ws + OFF_HP;
  float* hT      = ws + OFF_HT;
  float* ys_part = ws + OFF_YSP;
  float* ys_f    = ws + OFF_YSF;

  k_phinorm<<<E, 256, 0, stream>>>(phi, scale, phT);
  k_logits<<<(B * M) / 128, 256, 0, stream>>>(x, phT, invn, logits, pmax, psum);
  k_dispatch<<<B * NSX * 2, 256, 0, stream>>>(x, logits, invn, pmax, xs_part);
  k_xsred<<<B * E, 256, 0, stream>>>(xs_part, pmax, psum, xs_f);
  k_gemm1<<<E * 2 * NK1, 256, 0, stream>>>(w1, xs_f, h_part);
  k_gelu<<<E * 8, 256, 0, stream>>>(h_part, b1, hT);
  k_gemm2<<<E * NK2, 256, 0, stream>>>(w2, hT, ys_part);
  k_ysred<<<E * 4, 256, 0, stream>>>(ys_part, ys_f);
  k_combine<<<B * 32 * 4, 256, 0, stream>>>(logits, ys_f, b2, y);
}

// Round 5
// 239.828 us; speedup vs baseline: 1.5873x; 1.0779x over previous
//
#include <hip/hip_runtime.h>
#include <hip/hip_bf16.h>
#include <math.h>

// Soft-MoE forward. B=8, M=4096, D=512, E=64, P=1, H=2048.
// R5: bf16 xn cache (dispatch no longer reads fp32 x), gemm1+gelu fused
// (h_part eliminated), bf16 logits/xs_part/ys_part. fp32 accumulation
// everywhere; fp32 hT / xs_f / ys_f.

namespace {
constexpr int B = 8, M = 4096, D = 512, E = 64, H = 2048;
constexpr int NSD = 32;   // logits/dstat m-splits (128 rows each)
constexpr int NSX = 32;   // dispatch m-splits
constexpr int NK2 = 16;   // gemm2 k-slabs

constexpr size_t OFF_INVN = 0;                                  // B*M f32
constexpr size_t OFF_PHT  = OFF_INVN + (size_t)B * M;           // D*E bf16
constexpr size_t OFF_XNB  = OFF_PHT  + (size_t)D * E / 2;       // B*M*D bf16
constexpr size_t OFF_LOGB = OFF_XNB  + (size_t)B * M * D / 2;   // B*M*E bf16
constexpr size_t OFF_PMAX = OFF_LOGB + (size_t)B * M * E / 2;   // B*NSD*E f32
constexpr size_t OFF_PSUM = OFF_PMAX + (size_t)B * NSD * E;
constexpr size_t OFF_XSP  = OFF_PSUM + (size_t)B * NSD * E;     // NSX*B*E*D bf16
constexpr size_t OFF_XSF  = OFF_XSP  + (size_t)NSX * B * E * D / 2; // E*D*B f32
constexpr size_t OFF_HT   = OFF_XSF  + (size_t)E * D * B;       // E*H*B f32
constexpr size_t OFF_YSP  = OFF_HT   + (size_t)E * H * B;       // NK2*E*D*B bf16
constexpr size_t OFF_YSF  = OFF_YSP  + (size_t)NK2 * E * D * B / 2; // B*E*D f32
constexpr size_t WS_FLOATS = OFF_YSF + (size_t)E * D * B;       // ~70 MB
} // namespace

typedef __attribute__((ext_vector_type(8))) short short8v;
typedef __attribute__((ext_vector_type(4))) float f32x4;

static __device__ inline unsigned short f2bf(float f) {
  __hip_bfloat16 h = __float2bfloat16(f);
  return *reinterpret_cast<unsigned short*>(&h);
}
static __device__ inline float bf2f(unsigned short u) {
  unsigned int x = ((unsigned int)u) << 16;
  return __uint_as_float(x);
}

// ---- K2: phT[e][d] = bf16(scale * l2norm(phi, axis=0)). grid 64, block 256 ----
__global__ __launch_bounds__(256) void k_phinorm(const float* __restrict__ phi,
                                                 const float* __restrict__ scale,
                                                 unsigned short* __restrict__ phT) {
  int e = blockIdx.x;
  int t = threadIdx.x;
  float v0 = phi[(size_t)t * E + e];
  float v1 = phi[(size_t)(t + 256) * E + e];
  __shared__ float red[256];
  red[t] = v0 * v0 + v1 * v1;
  __syncthreads();
  for (int s = 128; s; s >>= 1) {
    if (t < s) red[t] += red[t + s];
    __syncthreads();
  }
  float inv = scale[0] / fmaxf(sqrtf(red[0]), 1e-12f);
  phT[(size_t)e * D + t]       = f2bf(v0 * inv);
  phT[(size_t)e * D + t + 256] = f2bf(v1 * inv);
}

// ---- K3: fused rownorm + logits (bf16 MFMA) + d-softmax partials + xnb export ----
// grid 256 (128-row tiles), block 256 = 4 waves; wave w owns rows w*32..w*32+31.
__global__ __launch_bounds__(256) void k_logits(const float* __restrict__ x,
                                                const unsigned short* __restrict__ phT,
                                                float* __restrict__ invn,
                                                unsigned short* __restrict__ xnb,
                                                unsigned short* __restrict__ logitsb,
                                                float* __restrict__ pmax,
                                                float* __restrict__ psum) {
  __shared__ __align__(16) unsigned short phs[64 * 520];  // [e][k] pad 520
  __shared__ __align__(16) unsigned short xA[128 * 56];   // [row][k] pad 56
  __shared__ float invs[128];
  __shared__ float smax[4][64];
  __shared__ float bmax[64];
  int t = threadIdx.x;
  int lane = t & 63, w = t >> 6;
  int rowbase = blockIdx.x * 128;
  {
    int e = t >> 2, q0 = (t & 3) * 16;
#pragma unroll
    for (int q = 0; q < 16; q++)
      *(short8v*)&phs[e * 520 + (q0 + q) * 8] =
          *(const short8v*)&phT[(size_t)e * D + (q0 + q) * 8];
  }
  int srow = t >> 1;        // 0..127
  int kb = (t & 1) * 16;    // k sub-offset within 32-chunk
  float ss = 0.f;
  f32x4 acc[2][4];
#pragma unroll
  for (int i = 0; i < 2; i++)
#pragma unroll
    for (int j = 0; j < 4; j++) acc[i][j] = (f32x4)(0.f);
  int kg = lane >> 4;       // 0..3 (k-group of 8)
  int l15 = lane & 15;
  for (int ks = 0; ks < 16; ks++) {
    __syncthreads();
    const float4* xp = (const float4*)(x + (size_t)(rowbase + srow) * D + ks * 32 + kb);
#pragma unroll
    for (int q = 0; q < 4; q++) {
      float4 v = xp[q];
      ss += v.x * v.x + v.y * v.y + v.z * v.z + v.w * v.w;
      ushort4 u;
      u.x = f2bf(v.x); u.y = f2bf(v.y); u.z = f2bf(v.z); u.w = f2bf(v.w);
      *(ushort4*)&xA[srow * 56 + kb + q * 4] = u;
    }
    __syncthreads();
    // export bf16 x chunk to global (LDS readback, fire-and-forget stores)
    {
      uint4 x0 = *(uint4*)&xA[srow * 56 + kb];
      uint4 x1 = *(uint4*)&xA[srow * 56 + kb + 8];
      size_t go = (size_t)(rowbase + srow) * D + ks * 32 + kb;
      *(uint4*)&xnb[go]     = x0;
      *(uint4*)&xnb[go + 8] = x1;
    }
    short8v a0 = *(short8v*)&xA[(w * 32 + l15) * 56 + kg * 8];
    short8v a1 = *(short8v*)&xA[(w * 32 + 16 + l15) * 56 + kg * 8];
    short8v b0 = *(short8v*)&phs[(l15)      * 520 + ks * 32 + kg * 8];
    short8v b1 = *(short8v*)&phs[(16 + l15) * 520 + ks * 32 + kg * 8];
    short8v b2 = *(short8v*)&phs[(32 + l15) * 520 + ks * 32 + kg * 8];
    short8v b3 = *(short8v*)&phs[(48 + l15) * 520 + ks * 32 + kg * 8];
    acc[0][0] = __builtin_amdgcn_mfma_f32_16x16x32_bf16(a0, b0, acc[0][0], 0, 0, 0);
    acc[0][1] = __builtin_amdgcn_mfma_f32_16x16x32_bf16(a0, b1, acc[0][1], 0, 0, 0);
    acc[0][2] = __builtin_amdgcn_mfma_f32_16x16x32_bf16(a0, b2, acc[0][2], 0, 0, 0);
    acc[0][3] = __builtin_amdgcn_mfma_f32_16x16x32_bf16(a0, b3, acc[0][3], 0, 0, 0);
    acc[1][0] = __builtin_amdgcn_mfma_f32_16x16x32_bf16(a1, b0, acc[1][0], 0, 0, 0);
    acc[1][1] = __builtin_amdgcn_mfma_f32_16x16x32_bf16(a1, b1, acc[1][1], 0, 0, 0);
    acc[1][2] = __builtin_amdgcn_mfma_f32_16x16x32_bf16(a1, b2, acc[1][2], 0, 0, 0);
    acc[1][3] = __builtin_amdgcn_mfma_f32_16x16x32_bf16(a1, b3, acc[1][3], 0, 0, 0);
  }
  ss += __shfl_xor(ss, 1, 64);
  float iv = 1.0f / fmaxf(sqrtf(ss), 1e-12f);
  if ((t & 1) == 0) {
    invs[srow] = iv;
    invn[rowbase + srow] = iv;
  }
  __syncthreads();
  float lm[4] = {-1e30f, -1e30f, -1e30f, -1e30f};
  int rsub = (lane >> 4) * 4;
#pragma unroll
  for (int fi = 0; fi < 2; fi++)
#pragma unroll
    for (int r = 0; r < 4; r++) {
      int row = w * 32 + fi * 16 + rsub + r;
      float ivr = invs[row];
#pragma unroll
      for (int eg = 0; eg < 4; eg++) {
        float v = acc[fi][eg][r] * ivr;
        logitsb[(size_t)(rowbase + row) * E + eg * 16 + l15] = f2bf(v);
        lm[eg] = fmaxf(lm[eg], v);
      }
    }
#pragma unroll
  for (int eg = 0; eg < 4; eg++) {
    lm[eg] = fmaxf(lm[eg], __shfl_xor(lm[eg], 16, 64));
    lm[eg] = fmaxf(lm[eg], __shfl_xor(lm[eg], 32, 64));
  }
  if (lane < 16)
#pragma unroll
    for (int eg = 0; eg < 4; eg++) smax[w][eg * 16 + lane] = lm[eg];
  __syncthreads();
  if (t < 64)
    bmax[t] = fmaxf(fmaxf(smax[0][t], smax[1][t]), fmaxf(smax[2][t], smax[3][t]));
  __syncthreads();
  float ps[4] = {0.f, 0.f, 0.f, 0.f};
#pragma unroll
  for (int fi = 0; fi < 2; fi++)
#pragma unroll
    for (int r = 0; r < 4; r++) {
      int row = w * 32 + fi * 16 + rsub + r;
      float ivr = invs[row];
#pragma unroll
      for (int eg = 0; eg < 4; eg++)
        ps[eg] += __expf(acc[fi][eg][r] * ivr - bmax[eg * 16 + l15]);
    }
#pragma unroll
  for (int eg = 0; eg < 4; eg++) {
    ps[eg] += __shfl_xor(ps[eg], 16, 64);
    ps[eg] += __shfl_xor(ps[eg], 32, 64);
  }
  __syncthreads();
  if (lane < 16)
#pragma unroll
    for (int eg = 0; eg < 4; eg++) smax[w][eg * 16 + lane] = ps[eg];
  __syncthreads();
  if (t < 64) {
    pmax[(size_t)blockIdx.x * 64 + t] = bmax[t];
    psum[(size_t)blockIdx.x * 64 + t] =
        smax[0][t] + smax[1][t] + smax[2][t] + smax[3][t];
  }
}

// ---- K5: dispatch partial: xs_part[ms][b][e][d](bf16) over 128-m split ----
// grid B*NSX*2=512 (dg = 256-col half), block 256; thread tile 8e x 8d.
__global__ __launch_bounds__(256) void k_dispatch(const unsigned short* __restrict__ xnb,
                                                  const unsigned short* __restrict__ logitsb,
                                                  const float* __restrict__ invn,
                                                  const float* __restrict__ pmax,
                                                  unsigned short* __restrict__ xs_part) {
  __shared__ float wexp[32][68];
  __shared__ float xt[32][260];
  __shared__ float dmx[64];
  __shared__ float invs[128];
  int t = threadIdx.x;
  int blk = blockIdx.x;
  int dg = blk & 1, ms = (blk >> 1) & 31, b = blk >> 6;
  int m0 = ms * 128;
  if (t < 64) {
    float g = pmax[((size_t)b * NSD) * 64 + t];
    for (int s = 1; s < NSD; s++)
      g = fmaxf(g, pmax[((size_t)(b * NSD + s)) * 64 + t]);
    dmx[t] = g;
  }
  if (t < 128) invs[t] = invn[b * M + m0 + t];
  float acc[8][8];
#pragma unroll
  for (int i = 0; i < 8; i++)
#pragma unroll
    for (int j = 0; j < 8; j++) acc[i][j] = 0.f;
  int e0 = (t & 7) * 8, d0 = (t >> 3) * 8;
  for (int c = 0; c < 4; c++) {
    int mr = m0 + c * 32;
    __syncthreads();
    {  // stage exp weights [32][64] from bf16 logits
      int rr = t >> 3, ew = (t & 7) * 8;
      short8v lv = *(const short8v*)&logitsb[((size_t)(b * M + mr + rr)) * E + ew];
#pragma unroll
      for (int q = 0; q < 8; q++)
        wexp[rr][ew + q] = __expf(bf2f((unsigned short)lv[q]) - dmx[ew + q]);
    }
#pragma unroll
    for (int k = 0; k < 4; k++) {  // stage xn tile [32][256] from bf16 x
      int f8 = t + 256 * k;
      int r = f8 >> 5, c8 = f8 & 31;
      short8v v8 = *(const short8v*)&xnb[((size_t)(b * M + mr + r)) * D + dg * 256 + c8 * 8];
      float iv = invs[c * 32 + r];
      float4 lo, hi;
      lo.x = bf2f((unsigned short)v8[0]) * iv; lo.y = bf2f((unsigned short)v8[1]) * iv;
      lo.z = bf2f((unsigned short)v8[2]) * iv; lo.w = bf2f((unsigned short)v8[3]) * iv;
      hi.x = bf2f((unsigned short)v8[4]) * iv; hi.y = bf2f((unsigned short)v8[5]) * iv;
      hi.z = bf2f((unsigned short)v8[6]) * iv; hi.w = bf2f((unsigned short)v8[7]) * iv;
      *(float4*)&xt[r][c8 * 8]     = lo;
      *(float4*)&xt[r][c8 * 8 + 4] = hi;
    }
    __syncthreads();
#pragma unroll 2
    for (int r = 0; r < 32; r++) {
      float a8[8], x8[8];
      *(float4*)&a8[0] = *(float4*)&wexp[r][e0];
      *(float4*)&a8[4] = *(float4*)&wexp[r][e0 + 4];
      *(float4*)&x8[0] = *(float4*)&xt[r][d0];
      *(float4*)&x8[4] = *(float4*)&xt[r][d0 + 4];
#pragma unroll
      for (int i = 0; i < 8; i++)
#pragma unroll
        for (int j = 0; j < 8; j++) acc[i][j] += a8[i] * x8[j];
    }
  }
  unsigned short* outp = xs_part + ((size_t)ms * B + b) * E * D;
#pragma unroll
  for (int i = 0; i < 8; i++) {
    unsigned short us[8];
#pragma unroll
    for (int j = 0; j < 8; j++) us[j] = f2bf(acc[i][j]);
    *(uint4*)(outp + (size_t)(e0 + i) * D + dg * 256 + d0) = *(uint4*)us;
  }
}

// ---- K5b: xs_f[e][d][b] = (sum_ms xs_part)/dsum, dsum inline. grid B*E=512 ----
__global__ __launch_bounds__(256) void k_xsred(const unsigned short* __restrict__ xs_part,
                                               const float* __restrict__ pmax,
                                               const float* __restrict__ psum,
                                               float* __restrict__ xs_f) {
  int blk = blockIdx.x;
  int b = blk >> 6, e = blk & 63;
  int t = threadIdx.x;
  float gm = -1e30f;
  for (int s = 0; s < NSD; s++)
    gm = fmaxf(gm, pmax[((size_t)(b * NSD + s)) * 64 + e]);
  float gs = 0.f;
  for (int s = 0; s < NSD; s++)
    gs += psum[((size_t)(b * NSD + s)) * 64 + e] *
          __expf(pmax[((size_t)(b * NSD + s)) * 64 + e] - gm);
  float inv = 1.0f / gs;
  size_t base = (((size_t)b * E + e) * D) / 2 + t;  // uint (2 bf16) units
  size_t slab = ((size_t)B * E * D) / 2;
  float a0 = 0.f, a1 = 0.f;
  const unsigned int* pp = (const unsigned int*)xs_part;
  for (int ms = 0; ms < NSX; ms++) {
    unsigned int v = pp[(size_t)ms * slab + base];
    a0 += bf2f((unsigned short)(v & 0xffff));
    a1 += bf2f((unsigned short)(v >> 16));
  }
  int d = t * 2;
  xs_f[((size_t)e * D + d) * B + b]     = a0 * inv;
  xs_f[((size_t)e * D + d + 1) * B + b] = a1 * inv;
}

// ---- K6: fused gemm1+gelu: hT[e][j][b] complete per block. grid E*16=1024 ----
// block 256 = 8 d-octants x 32 j-threads; LDS tree reduce; gelu in octant 0.
__global__ __launch_bounds__(256) void k_gemm1g(const float* __restrict__ w1,
                                                const float* __restrict__ b1,
                                                const float* __restrict__ xs_f,
                                                float* __restrict__ hT) {
  __shared__ float xsm[512 * 8];         // 16 KB
  __shared__ float rbuf[4 * 32 * 33];    // 16.5 KB (padded rows)
  int blk = blockIdx.x;
  int e = blk >> 4, hs = blk & 15;
  int t = threadIdx.x;
  const float4* xsrc = (const float4*)(xs_f + (size_t)e * D * B);
#pragma unroll
  for (int k = 0; k < 4; k++) ((float4*)xsm)[t + 256 * k] = xsrc[t + 256 * k];
  __syncthreads();
  int oct = t >> 5, jt = t & 31;
  int j0 = hs * 128 + jt * 4;
  const float* wp = w1 + ((size_t)e * D + oct * 64) * H + j0;
  const float* xb = xsm + oct * 64 * 8;
  float acc[4][8];
#pragma unroll
  for (int i = 0; i < 4; i++)
#pragma unroll
    for (int j = 0; j < 8; j++) acc[i][j] = 0.f;
#pragma unroll 8
  for (int d = 0; d < 64; d++) {
    float4 w = *(const float4*)(wp + (size_t)d * H);
    float x8[8];
    *(float4*)&x8[0] = *(float4*)&xb[d * 8];
    *(float4*)&x8[4] = *(float4*)&xb[d * 8 + 4];
#pragma unroll
    for (int bb = 0; bb < 8; bb++) {
      acc[0][bb] += w.x * x8[bb]; acc[1][bb] += w.y * x8[bb];
      acc[2][bb] += w.z * x8[bb]; acc[3][bb] += w.w * x8[bb];
    }
  }
  // tree reduce over octants: (4-7)->(0-3), (2-3)->(0-1), (1)->(0)
  if (oct >= 4) {
    float* rb = &rbuf[((oct - 4) * 32 + jt) * 33];
#pragma unroll
    for (int i = 0; i < 4; i++) {
      *(float4*)(rb + i * 8)     = *(float4*)&acc[i][0];
      *(float4*)(rb + i * 8 + 4) = *(float4*)&acc[i][4];
    }
  }
  __syncthreads();
  if (oct < 4) {
    const float* rb = &rbuf[(oct * 32 + jt) * 33];
#pragma unroll
    for (int i = 0; i < 4; i++)
#pragma unroll
      for (int j = 0; j < 8; j++) acc[i][j] += rb[i * 8 + j];
  }
  __syncthreads();
  if (oct == 2 || oct == 3) {
    float* rb = &rbuf[((oct - 2) * 32 + jt) * 33];
#pragma unroll
    for (int i = 0; i < 4; i++) {
      *(float4*)(rb + i * 8)     = *(float4*)&acc[i][0];
      *(float4*)(rb + i * 8 + 4) = *(float4*)&acc[i][4];
    }
  }
  __syncthreads();
  if (oct < 2) {
    const float* rb = &rbuf[(oct * 32 + jt) * 33];
#pragma unroll
    for (int i = 0; i < 4; i++)
#pragma unroll
      for (int j = 0; j < 8; j++) acc[i][j] += rb[i * 8 + j];
  }
  __syncthreads();
  if (oct == 1) {
    float* rb = &rbuf[jt * 33];
#pragma unroll
    for (int i = 0; i < 4; i++) {
      *(float4*)(rb + i * 8)     = *(float4*)&acc[i][0];
      *(float4*)(rb + i * 8 + 4) = *(float4*)&acc[i][4];
    }
  }
  __syncthreads();
  if (oct == 0) {
    const float* rb = &rbuf[jt * 33];
    float4 bi = *(const float4*)(b1 + (size_t)e * H + j0);
    float bv[4] = {bi.x, bi.y, bi.z, bi.w};
    float* op = hT + ((size_t)e * H + j0) * B;
#pragma unroll
    for (int i = 0; i < 4; i++) {
      float o[8];
#pragma unroll
      for (int j = 0; j < 8; j++) {
        float v = acc[i][j] + rb[i * 8 + j] + bv[i];
        o[j] = 0.5f * v * (1.0f + erff(v * 0.70710678118654752f));
      }
      *(float4*)(op + i * 8)     = *(float4*)&o[0];
      *(float4*)(op + i * 8 + 4) = *(float4*)&o[4];
    }
  }
}

// ---- K7: gemm2 slab partial (128 k-rows, kk halves combined in LDS) -> bf16.
// grid E*16=1024, block 256; writes ys_part[ks][e][d][b] bf16.
__global__ __launch_bounds__(256) void k_gemm2(const float* __restrict__ w2,
                                               const float* __restrict__ hT,
                                               unsigned short* __restrict__ ys_part) {
  int blk = blockIdx.x;
  int ks = blk & 15, e = blk >> 4;
  int t = threadIdx.x;
  __shared__ float hsm[128 * 8];   // hT slab [128 k][8 b]
  __shared__ float rbuf[128 * 32]; // kk=1 partials
  ((float4*)hsm)[t] = ((const float4*)(hT + ((size_t)e * H + ks * 128) * B))[t];
  __syncthreads();
  int kk = t >> 7, dq = t & 127;
  int d0 = dq * 4;
  const float* wp = w2 + ((size_t)e * H + ks * 128 + kk * 64) * D + d0;
  const float* hb = hsm + kk * 64 * 8;
  float acc[4][8];
#pragma unroll
  for (int i = 0; i < 4; i++)
#pragma unroll
    for (int j = 0; j < 8; j++) acc[i][j] = 0.f;
#pragma unroll 8
  for (int k = 0; k < 64; k++) {
    float4 w = *(const float4*)(wp + (size_t)k * D);
    float h8[8];
    *(float4*)&h8[0] = *(float4*)&hb[k * 8];
    *(float4*)&h8[4] = *(float4*)&hb[k * 8 + 4];
#pragma unroll
    for (int bb = 0; bb < 8; bb++) {
      acc[0][bb] += w.x * h8[bb]; acc[1][bb] += w.y * h8[bb];
      acc[2][bb] += w.z * h8[bb]; acc[3][bb] += w.w * h8[bb];
    }
  }
  if (kk) {
#pragma unroll
    for (int i = 0; i < 4; i++) {
      *(float4*)&rbuf[dq * 32 + i * 8]     = *(float4*)&acc[i][0];
      *(float4*)&rbuf[dq * 32 + i * 8 + 4] = *(float4*)&acc[i][4];
    }
  }
  __syncthreads();
  if (!kk) {
    unsigned short* op = ys_part + (((size_t)ks * E + e) * D + d0) * B;
#pragma unroll
    for (int i = 0; i < 4; i++) {
      unsigned short us[8];
#pragma unroll
      for (int j = 0; j < 8; j++)
        us[j] = f2bf(acc[i][j] + rbuf[dq * 32 + i * 8 + j]);
      *(uint4*)(op + (size_t)i * 8) = *(uint4*)us;
    }
  }
}

// ---- K7b: ys_f[b][e][d] = sum_ks ys_part (b2 added in combine). grid E*4 ----
__global__ __launch_bounds__(256) void k_ysred(const unsigned short* __restrict__ ys_part,
                                               float* __restrict__ ys_f) {
  int e = blockIdx.x >> 2, kq = blockIdx.x & 3;
  int t = threadIdx.x;
  int i4 = kq * 256 + t;  // ushort4 group within [512 d][8 b] slab
  float a[4] = {0.f, 0.f, 0.f, 0.f};
  for (int ks = 0; ks < NK2; ks++) {
    const unsigned short* q = ys_part + ((size_t)ks * E + e) * D * B;
    ushort4 v = *(const ushort4*)(q + (size_t)i4 * 4);
    a[0] += bf2f(v.x); a[1] += bf2f(v.y); a[2] += bf2f(v.z); a[3] += bf2f(v.w);
  }
  int d = i4 >> 1, bh = (i4 & 1) * 4;
  ys_f[((size_t)(bh + 0) * E + e) * D + d] = a[0];
  ys_f[((size_t)(bh + 1) * E + e) * D + d] = a[1];
  ys_f[((size_t)(bh + 2) * E + e) * D + d] = a[2];
  ys_f[((size_t)(bh + 3) * E + e) * D + d] = a[3];
}

// ---- K8: y[b][m][d] = sum_e softmax_e(L)[e] * (ys_f[b][e][d] + b2[e][d]) ----
__global__ __launch_bounds__(256) void k_combine(const unsigned short* __restrict__ logitsb,
                                                 const float* __restrict__ ys_f,
                                                 const float* __restrict__ b2,
                                                 float* __restrict__ y) {
  __shared__ float ysb[64][132];
  __shared__ float cT[64][68];
  __shared__ float red[64][4];
  __shared__ float gmx[64], gsm[64];
  int t = threadIdx.x;
  int blk = blockIdx.x;
  int dg = blk & 3, ms = (blk >> 2) & 31, b = blk >> 7;
  int m0 = ms * 128;
#pragma unroll
  for (int k = 0; k < 8; k++) {
    int f4 = t + 256 * k;
    int e = f4 >> 5, ci = f4 & 31;
    float4 v = *(const float4*)(ys_f + ((size_t)(b * E + e)) * D + dg * 128 + ci * 4);
    float4 bi = *(const float4*)(b2 + (size_t)e * D + dg * 128 + ci * 4);
    v.x += bi.x; v.y += bi.y; v.z += bi.z; v.w += bi.w;
    *(float4*)&ysb[e][ci * 4] = v;
  }
  int r0 = (t & 7) * 8;
  int d0 = (t >> 3) * 4;
  int row = t >> 2;
  int sub = t & 3;
  for (int ch = 0; ch < 2; ch++) {
    int mr = m0 + ch * 64;
    float r16[16];
    const unsigned short* Lr = logitsb + ((size_t)(b * M + mr + row)) * E + sub * 16;
    short8v l0 = *(const short8v*)Lr;
    short8v l1 = *(const short8v*)(Lr + 8);
#pragma unroll
    for (int k = 0; k < 8; k++) {
      r16[k]     = bf2f((unsigned short)l0[k]);
      r16[8 + k] = bf2f((unsigned short)l1[k]);
    }
    float lm = -1e30f;
#pragma unroll
    for (int k = 0; k < 16; k++) lm = fmaxf(lm, r16[k]);
    __syncthreads();
    red[row][sub] = lm;
    __syncthreads();
    if (sub == 0) {
      float g = fmaxf(fmaxf(red[row][0], red[row][1]), fmaxf(red[row][2], red[row][3]));
      gmx[row] = g;
    }
    __syncthreads();
    float g = gmx[row];
    float ls = 0.f;
#pragma unroll
    for (int k = 0; k < 16; k++) {
      r16[k] = __expf(r16[k] - g);
      ls += r16[k];
    }
    __syncthreads();
    red[row][sub] = ls;
    __syncthreads();
    if (sub == 0)
      gsm[row] = 1.0f / (red[row][0] + red[row][1] + red[row][2] + red[row][3]);
    __syncthreads();
    float is = gsm[row];
#pragma unroll
    for (int k = 0; k < 16; k++) cT[sub * 16 + k][row] = r16[k] * is;
    __syncthreads();
    float acc[8][4];
#pragma unroll
    for (int i = 0; i < 8; i++)
#pragma unroll
      for (int j = 0; j < 4; j++) acc[i][j] = 0.f;
#pragma unroll 4
    for (int e = 0; e < 64; e++) {
      float c8[8], y4[4];
      *(float4*)&c8[0] = *(float4*)&cT[e][r0];
      *(float4*)&c8[4] = *(float4*)&cT[e][r0 + 4];
      *(float4*)&y4[0] = *(float4*)&ysb[e][d0];
#pragma unroll
      for (int i = 0; i < 8; i++)
#pragma unroll
        for (int j = 0; j < 4; j++) acc[i][j] += c8[i] * y4[j];
    }
#pragma unroll
    for (int i = 0; i < 8; i++) {
      float* op = y + ((size_t)(b * M + mr + r0 + i)) * D + dg * 128 + d0;
      *(float4*)op = *(float4*)&acc[i][0];
    }
  }
}

extern "C" void kernel_launch(void* const* d_in, const int* in_sizes, int n_in,
                              void* d_out, int out_size, void* d_ws, size_t ws_size,
                              hipStream_t stream) {
  const float* x     = (const float*)d_in[0];
  const float* phi   = (const float*)d_in[1];
  const float* scale = (const float*)d_in[2];
  const float* w1    = (const float*)d_in[3];
  const float* b1    = (const float*)d_in[4];
  const float* w2    = (const float*)d_in[5];
  const float* b2    = (const float*)d_in[6];
  float* y = (float*)d_out;
  float* ws = (float*)d_ws;
  (void)in_sizes; (void)n_in; (void)out_size; (void)ws_size;

  float* invn            = ws + OFF_INVN;
  unsigned short* phT    = (unsigned short*)(ws + OFF_PHT);
  unsigned short* xnb    = (unsigned short*)(ws + OFF_XNB);
  unsigned short* logitsb = (unsigned short*)(ws + OFF_LOGB);
  float* pmax    = ws + OFF_PMAX;
  float* psum    = ws + OFF_PSUM;
  unsigned short* xs_part = (unsigned short*)(ws + OFF_XSP);
  float* xs_f    = ws + OFF_XSF;
  float* hT      = ws + OFF_HT;
  unsigned short* ys_part = (unsigned short*)(ws + OFF_YSP);
  float* ys_f    = ws + OFF_YSF;

  k_phinorm<<<E, 256, 0, stream>>>(phi, scale, phT);
  k_logits<<<(B * M) / 128, 256, 0, stream>>>(x, phT, invn, xnb, logitsb, pmax, psum);
  k_dispatch<<<B * NSX * 2, 256, 0, stream>>>(xnb, logitsb, invn, pmax, xs_part);
  k_xsred<<<B * E, 256, 0, stream>>>(xs_part, pmax, psum, xs_f);
  k_gemm1g<<<E * 16, 256, 0, stream>>>(w1, b1, xs_f, hT);
  k_gemm2<<<E * NK2, 256, 0, stream>>>(w2, hT, ys_part);
  k_ysred<<<E * 4, 256, 0, stream>>>(ys_part, ys_f);
  k_combine<<<B * 32 * 4, 256, 0, stream>>>(logitsb, ys_f, b2, y);
}

// Round 6
// 202.260 us; speedup vs baseline: 1.8821x; 1.1857x over previous
//
#include <hip/hip_runtime.h>
#include <hip/hip_bf16.h>
#include <math.h>

// Soft-MoE forward. B=8, M=4096, D=512, E=64, P=1, H=2048.
// R6: dispatch + combine converted to bf16 MFMA (fp32 accumulate).
// ysred emits ysT[b][d][e] bf16 (+b2). invn folded into dispatch weights.

namespace {
constexpr int B = 8, M = 4096, D = 512, E = 64, H = 2048;
constexpr int NSD = 32;   // logits/dstat m-splits (128 rows each)
constexpr int NSX = 32;   // dispatch m-splits
constexpr int NK2 = 16;   // gemm2 k-slabs

constexpr size_t OFF_INVN = 0;                                  // B*M f32
constexpr size_t OFF_PHT  = OFF_INVN + (size_t)B * M;           // D*E bf16
constexpr size_t OFF_XNB  = OFF_PHT  + (size_t)D * E / 2;       // B*M*D bf16
constexpr size_t OFF_LOGB = OFF_XNB  + (size_t)B * M * D / 2;   // B*M*E bf16
constexpr size_t OFF_PMAX = OFF_LOGB + (size_t)B * M * E / 2;   // B*NSD*E f32
constexpr size_t OFF_PSUM = OFF_PMAX + (size_t)B * NSD * E;
constexpr size_t OFF_XSP  = OFF_PSUM + (size_t)B * NSD * E;     // NSX*B*E*D bf16
constexpr size_t OFF_XSF  = OFF_XSP  + (size_t)NSX * B * E * D / 2; // E*D*B f32
constexpr size_t OFF_HT   = OFF_XSF  + (size_t)E * D * B;       // E*H*B f32
constexpr size_t OFF_YSP  = OFF_HT   + (size_t)E * H * B;       // NK2*E*D*B bf16
constexpr size_t OFF_YST  = OFF_YSP  + (size_t)NK2 * E * D * B / 2; // B*D*E bf16
constexpr size_t WS_FLOATS = OFF_YST + (size_t)B * D * E / 2;   // ~70 MB
} // namespace

typedef __attribute__((ext_vector_type(8))) short short8v;
typedef __attribute__((ext_vector_type(4))) float f32x4;

static __device__ inline unsigned short f2bf(float f) {
  __hip_bfloat16 h = __float2bfloat16(f);
  return *reinterpret_cast<unsigned short*>(&h);
}
static __device__ inline float bf2f(unsigned short u) {
  unsigned int x = ((unsigned int)u) << 16;
  return __uint_as_float(x);
}
static __device__ inline short8v ld4w(const unsigned int* p, int a) {
  union { unsigned int u[4]; short8v v; } x;
  x.u[0] = p[a]; x.u[1] = p[a + 1]; x.u[2] = p[a + 2]; x.u[3] = p[a + 3];
  return x.v;
}

// ---- K2: phT[e][d] = bf16(scale * l2norm(phi, axis=0)). grid 64, block 256 ----
__global__ __launch_bounds__(256) void k_phinorm(const float* __restrict__ phi,
                                                 const float* __restrict__ scale,
                                                 unsigned short* __restrict__ phT) {
  int e = blockIdx.x;
  int t = threadIdx.x;
  float v0 = phi[(size_t)t * E + e];
  float v1 = phi[(size_t)(t + 256) * E + e];
  __shared__ float red[256];
  red[t] = v0 * v0 + v1 * v1;
  __syncthreads();
  for (int s = 128; s; s >>= 1) {
    if (t < s) red[t] += red[t + s];
    __syncthreads();
  }
  float inv = scale[0] / fmaxf(sqrtf(red[0]), 1e-12f);
  phT[(size_t)e * D + t]       = f2bf(v0 * inv);
  phT[(size_t)e * D + t + 256] = f2bf(v1 * inv);
}

// ---- K3: fused rownorm + logits (bf16 MFMA) + d-softmax partials + xnb export ----
__global__ __launch_bounds__(256) void k_logits(const float* __restrict__ x,
                                                const unsigned short* __restrict__ phT,
                                                float* __restrict__ invn,
                                                unsigned short* __restrict__ xnb,
                                                unsigned short* __restrict__ logitsb,
                                                float* __restrict__ pmax,
                                                float* __restrict__ psum) {
  __shared__ __align__(16) unsigned short phs[64 * 520];  // [e][k] pad 520
  __shared__ __align__(16) unsigned short xA[128 * 56];   // [row][k] pad 56
  __shared__ float invs[128];
  __shared__ float smax[4][64];
  __shared__ float bmax[64];
  int t = threadIdx.x;
  int lane = t & 63, w = t >> 6;
  int rowbase = blockIdx.x * 128;
  {
    int e = t >> 2, q0 = (t & 3) * 16;
#pragma unroll
    for (int q = 0; q < 16; q++)
      *(short8v*)&phs[e * 520 + (q0 + q) * 8] =
          *(const short8v*)&phT[(size_t)e * D + (q0 + q) * 8];
  }
  int srow = t >> 1;
  int kb = (t & 1) * 16;
  float ss = 0.f;
  f32x4 acc[2][4];
#pragma unroll
  for (int i = 0; i < 2; i++)
#pragma unroll
    for (int j = 0; j < 4; j++) acc[i][j] = (f32x4)(0.f);
  int kg = lane >> 4;
  int l15 = lane & 15;
  for (int ks = 0; ks < 16; ks++) {
    __syncthreads();
    const float4* xp = (const float4*)(x + (size_t)(rowbase + srow) * D + ks * 32 + kb);
#pragma unroll
    for (int q = 0; q < 4; q++) {
      float4 v = xp[q];
      ss += v.x * v.x + v.y * v.y + v.z * v.z + v.w * v.w;
      ushort4 u;
      u.x = f2bf(v.x); u.y = f2bf(v.y); u.z = f2bf(v.z); u.w = f2bf(v.w);
      *(ushort4*)&xA[srow * 56 + kb + q * 4] = u;
    }
    __syncthreads();
    {
      uint4 x0 = *(uint4*)&xA[srow * 56 + kb];
      uint4 x1 = *(uint4*)&xA[srow * 56 + kb + 8];
      size_t go = (size_t)(rowbase + srow) * D + ks * 32 + kb;
      *(uint4*)&xnb[go]     = x0;
      *(uint4*)&xnb[go + 8] = x1;
    }
    short8v a0 = *(short8v*)&xA[(w * 32 + l15) * 56 + kg * 8];
    short8v a1 = *(short8v*)&xA[(w * 32 + 16 + l15) * 56 + kg * 8];
    short8v b0 = *(short8v*)&phs[(l15)      * 520 + ks * 32 + kg * 8];
    short8v b1 = *(short8v*)&phs[(16 + l15) * 520 + ks * 32 + kg * 8];
    short8v b2 = *(short8v*)&phs[(32 + l15) * 520 + ks * 32 + kg * 8];
    short8v b3 = *(short8v*)&phs[(48 + l15) * 520 + ks * 32 + kg * 8];
    acc[0][0] = __builtin_amdgcn_mfma_f32_16x16x32_bf16(a0, b0, acc[0][0], 0, 0, 0);
    acc[0][1] = __builtin_amdgcn_mfma_f32_16x16x32_bf16(a0, b1, acc[0][1], 0, 0, 0);
    acc[0][2] = __builtin_amdgcn_mfma_f32_16x16x32_bf16(a0, b2, acc[0][2], 0, 0, 0);
    acc[0][3] = __builtin_amdgcn_mfma_f32_16x16x32_bf16(a0, b3, acc[0][3], 0, 0, 0);
    acc[1][0] = __builtin_amdgcn_mfma_f32_16x16x32_bf16(a1, b0, acc[1][0], 0, 0, 0);
    acc[1][1] = __builtin_amdgcn_mfma_f32_16x16x32_bf16(a1, b1, acc[1][1], 0, 0, 0);
    acc[1][2] = __builtin_amdgcn_mfma_f32_16x16x32_bf16(a1, b2, acc[1][2], 0, 0, 0);
    acc[1][3] = __builtin_amdgcn_mfma_f32_16x16x32_bf16(a1, b3, acc[1][3], 0, 0, 0);
  }
  ss += __shfl_xor(ss, 1, 64);
  float iv = 1.0f / fmaxf(sqrtf(ss), 1e-12f);
  if ((t & 1) == 0) {
    invs[srow] = iv;
    invn[rowbase + srow] = iv;
  }
  __syncthreads();
  float lm[4] = {-1e30f, -1e30f, -1e30f, -1e30f};
  int rsub = (lane >> 4) * 4;
#pragma unroll
  for (int fi = 0; fi < 2; fi++)
#pragma unroll
    for (int r = 0; r < 4; r++) {
      int row = w * 32 + fi * 16 + rsub + r;
      float ivr = invs[row];
#pragma unroll
      for (int eg = 0; eg < 4; eg++) {
        float v = acc[fi][eg][r] * ivr;
        logitsb[(size_t)(rowbase + row) * E + eg * 16 + l15] = f2bf(v);
        lm[eg] = fmaxf(lm[eg], v);
      }
    }
#pragma unroll
  for (int eg = 0; eg < 4; eg++) {
    lm[eg] = fmaxf(lm[eg], __shfl_xor(lm[eg], 16, 64));
    lm[eg] = fmaxf(lm[eg], __shfl_xor(lm[eg], 32, 64));
  }
  if (lane < 16)
#pragma unroll
    for (int eg = 0; eg < 4; eg++) smax[w][eg * 16 + lane] = lm[eg];
  __syncthreads();
  if (t < 64)
    bmax[t] = fmaxf(fmaxf(smax[0][t], smax[1][t]), fmaxf(smax[2][t], smax[3][t]));
  __syncthreads();
  float ps[4] = {0.f, 0.f, 0.f, 0.f};
#pragma unroll
  for (int fi = 0; fi < 2; fi++)
#pragma unroll
    for (int r = 0; r < 4; r++) {
      int row = w * 32 + fi * 16 + rsub + r;
      float ivr = invs[row];
#pragma unroll
      for (int eg = 0; eg < 4; eg++)
        ps[eg] += __expf(acc[fi][eg][r] * ivr - bmax[eg * 16 + l15]);
    }
#pragma unroll
  for (int eg = 0; eg < 4; eg++) {
    ps[eg] += __shfl_xor(ps[eg], 16, 64);
    ps[eg] += __shfl_xor(ps[eg], 32, 64);
  }
  __syncthreads();
  if (lane < 16)
#pragma unroll
    for (int eg = 0; eg < 4; eg++) smax[w][eg * 16 + lane] = ps[eg];
  __syncthreads();
  if (t < 64) {
    pmax[(size_t)blockIdx.x * 64 + t] = bmax[t];
    psum[(size_t)blockIdx.x * 64 + t] =
        smax[0][t] + smax[1][t] + smax[2][t] + smax[3][t];
  }
}

// ---- K5: dispatch via MFMA. xs_part[ms][b][e][d] = sum_m wexp'[m][e]*xnb[m][d]
// where wexp' = exp(L-dmax)*invn (invn folded into K-side weight).
// grid B*NSX*2=512 (dg = 256-d half), block 256 = 4 waves.
__global__ __launch_bounds__(256) void k_dispatch(const unsigned short* __restrict__ xnb,
                                                  const unsigned short* __restrict__ logitsb,
                                                  const float* __restrict__ invn,
                                                  const float* __restrict__ pmax,
                                                  unsigned short* __restrict__ xs_part) {
  __shared__ unsigned int xT32[256 * 17];   // B^T: [d][m-pair], 17 w/row
  __shared__ unsigned int weT32[64 * 17];   // A:   [e][m-pair], 17 w/row
  __shared__ __align__(16) unsigned short rp[32 * 264];  // repack [e32][d 256+8]
  __shared__ float dmx[64];
  __shared__ float invs[128];
  int t = threadIdx.x;
  int lane = t & 63, w = t >> 6;
  int blk = blockIdx.x;
  int dg = blk & 1, ms = (blk >> 1) & 31, b = blk >> 6;
  int m0 = ms * 128;
  if (t < 64) {
    float g = pmax[((size_t)b * NSD) * 64 + t];
    for (int s = 1; s < NSD; s++)
      g = fmaxf(g, pmax[((size_t)(b * NSD + s)) * 64 + t]);
    dmx[t] = g;
  }
  if (t < 128) invs[t] = invn[b * M + m0 + t];
  int kg = lane >> 4, l15 = lane & 15;
  f32x4 acc[4][4];  // [etile][dtile]
#pragma unroll
  for (int i = 0; i < 4; i++)
#pragma unroll
    for (int j = 0; j < 4; j++) acc[i][j] = (f32x4)(0.f);
  for (int c = 0; c < 4; c++) {
    __syncthreads();
    // stage weT: 32 m x 64 e, m-pairs packed in u32 (lo=even m)
    {
      int mp = t >> 4, e4 = t & 15;
      int mrow = m0 + c * 32 + 2 * mp;
      ushort4 lv0 = *(const ushort4*)&logitsb[((size_t)(b * M + mrow)) * E + e4 * 4];
      ushort4 lv1 = *(const ushort4*)&logitsb[((size_t)(b * M + mrow + 1)) * E + e4 * 4];
      float iv0 = invs[c * 32 + 2 * mp], iv1 = invs[c * 32 + 2 * mp + 1];
      unsigned short a0 = f2bf(__expf(bf2f(lv0.x) - dmx[e4 * 4 + 0]) * iv0);
      unsigned short a1 = f2bf(__expf(bf2f(lv0.y) - dmx[e4 * 4 + 1]) * iv0);
      unsigned short a2 = f2bf(__expf(bf2f(lv0.z) - dmx[e4 * 4 + 2]) * iv0);
      unsigned short a3 = f2bf(__expf(bf2f(lv0.w) - dmx[e4 * 4 + 3]) * iv0);
      unsigned short b0 = f2bf(__expf(bf2f(lv1.x) - dmx[e4 * 4 + 0]) * iv1);
      unsigned short b1 = f2bf(__expf(bf2f(lv1.y) - dmx[e4 * 4 + 1]) * iv1);
      unsigned short b2 = f2bf(__expf(bf2f(lv1.z) - dmx[e4 * 4 + 2]) * iv1);
      unsigned short b3 = f2bf(__expf(bf2f(lv1.w) - dmx[e4 * 4 + 3]) * iv1);
      weT32[(e4 * 4 + 0) * 17 + mp] = (unsigned int)a0 | ((unsigned int)b0 << 16);
      weT32[(e4 * 4 + 1) * 17 + mp] = (unsigned int)a1 | ((unsigned int)b1 << 16);
      weT32[(e4 * 4 + 2) * 17 + mp] = (unsigned int)a2 | ((unsigned int)b2 << 16);
      weT32[(e4 * 4 + 3) * 17 + mp] = (unsigned int)a3 | ((unsigned int)b3 << 16);
    }
    // stage xT: 32 m x 256 d transposed, m-pairs packed (8 iters)
#pragma unroll
    for (int i = 0; i < 8; i++) {
      int flat = i * 256 + t;
      int mp = flat >> 7, d2 = flat & 127;
      int mrow = m0 + c * 32 + 2 * mp;
      unsigned int ua = *(const unsigned int*)&xnb[((size_t)(b * M + mrow)) * D + dg * 256 + d2 * 2];
      unsigned int ub = *(const unsigned int*)&xnb[((size_t)(b * M + mrow + 1)) * D + dg * 256 + d2 * 2];
      xT32[(2 * d2 + 0) * 17 + mp] = (ua & 0xffffu) | ((ub & 0xffffu) << 16);
      xT32[(2 * d2 + 1) * 17 + mp] = (ua >> 16) | (ub & 0xffff0000u);
    }
    __syncthreads();
    // MFMA: wave w covers d = w*64 .. w*64+63
    short8v afr[4];
#pragma unroll
    for (int et = 0; et < 4; et++)
      afr[et] = ld4w(weT32, (et * 16 + l15) * 17 + kg * 4);
#pragma unroll
    for (int dt = 0; dt < 4; dt++) {
      short8v bfr = ld4w(xT32, (w * 64 + dt * 16 + l15) * 17 + kg * 4);
#pragma unroll
      for (int et = 0; et < 4; et++)
        acc[et][dt] = __builtin_amdgcn_mfma_f32_16x16x32_bf16(afr[et], bfr, acc[et][dt], 0, 0, 0);
    }
  }
  // repack + coalesced store: two passes of 32 e
  unsigned short* outp = xs_part + ((size_t)ms * B + b) * E * D;
#pragma unroll
  for (int p = 0; p < 2; p++) {
    __syncthreads();
#pragma unroll
    for (int ei = 0; ei < 2; ei++) {
      int et = p * 2 + ei;
#pragma unroll
      for (int dt = 0; dt < 4; dt++)
#pragma unroll
        for (int r = 0; r < 4; r++) {
          int el = ei * 16 + (lane >> 4) * 4 + r;
          int d  = w * 64 + dt * 16 + l15;
          rp[el * 264 + d] = f2bf(acc[et][dt][r]);
        }
    }
    __syncthreads();
    int el = t >> 3, dc = t & 7;
#pragma unroll
    for (int cc = 0; cc < 4; cc++) {
      int chunk = cc * 8 + dc;
      uint4 v = *(uint4*)&rp[el * 264 + chunk * 8];
      *(uint4*)(outp + (size_t)(p * 32 + el) * D + dg * 256 + chunk * 8) = v;
    }
  }
}

// ---- K5b: xs_f[e][d][b] = (sum_ms xs_part)/dsum, dsum inline. grid B*E=512 ----
__global__ __launch_bounds__(256) void k_xsred(const unsigned short* __restrict__ xs_part,
                                               const float* __restrict__ pmax,
                                               const float* __restrict__ psum,
                                               float* __restrict__ xs_f) {
  int blk = blockIdx.x;
  int b = blk >> 6, e = blk & 63;
  int t = threadIdx.x;
  float gm = -1e30f;
  for (int s = 0; s < NSD; s++)
    gm = fmaxf(gm, pmax[((size_t)(b * NSD + s)) * 64 + e]);
  float gs = 0.f;
  for (int s = 0; s < NSD; s++)
    gs += psum[((size_t)(b * NSD + s)) * 64 + e] *
          __expf(pmax[((size_t)(b * NSD + s)) * 64 + e] - gm);
  float inv = 1.0f / gs;
  size_t base = (((size_t)b * E + e) * D) / 2 + t;
  size_t slab = ((size_t)B * E * D) / 2;
  float a0 = 0.f, a1 = 0.f;
  const unsigned int* pp = (const unsigned int*)xs_part;
  for (int ms = 0; ms < NSX; ms++) {
    unsigned int v = pp[(size_t)ms * slab + base];
    a0 += bf2f((unsigned short)(v & 0xffff));
    a1 += bf2f((unsigned short)(v >> 16));
  }
  int d = t * 2;
  xs_f[((size_t)e * D + d) * B + b]     = a0 * inv;
  xs_f[((size_t)e * D + d + 1) * B + b] = a1 * inv;
}

// ---- K6: fused gemm1+gelu. grid E*16=1024 ----
__global__ __launch_bounds__(256) void k_gemm1g(const float* __restrict__ w1,
                                                const float* __restrict__ b1,
                                                const float* __restrict__ xs_f,
                                                float* __restrict__ hT) {
  __shared__ float xsm[512 * 8];
  __shared__ float rbuf[4 * 32 * 33];
  int blk = blockIdx.x;
  int e = blk >> 4, hs = blk & 15;
  int t = threadIdx.x;
  const float4* xsrc = (const float4*)(xs_f + (size_t)e * D * B);
#pragma unroll
  for (int k = 0; k < 4; k++) ((float4*)xsm)[t + 256 * k] = xsrc[t + 256 * k];
  __syncthreads();
  int oct = t >> 5, jt = t & 31;
  int j0 = hs * 128 + jt * 4;
  const float* wp = w1 + ((size_t)e * D + oct * 64) * H + j0;
  const float* xb = xsm + oct * 64 * 8;
  float acc[4][8];
#pragma unroll
  for (int i = 0; i < 4; i++)
#pragma unroll
    for (int j = 0; j < 8; j++) acc[i][j] = 0.f;
#pragma unroll 8
  for (int d = 0; d < 64; d++) {
    float4 w = *(const float4*)(wp + (size_t)d * H);
    float x8[8];
    *(float4*)&x8[0] = *(float4*)&xb[d * 8];
    *(float4*)&x8[4] = *(float4*)&xb[d * 8 + 4];
#pragma unroll
    for (int bb = 0; bb < 8; bb++) {
      acc[0][bb] += w.x * x8[bb]; acc[1][bb] += w.y * x8[bb];
      acc[2][bb] += w.z * x8[bb]; acc[3][bb] += w.w * x8[bb];
    }
  }
  if (oct >= 4) {
    float* rb = &rbuf[((oct - 4) * 32 + jt) * 33];
#pragma unroll
    for (int i = 0; i < 4; i++) {
      *(float4*)(rb + i * 8)     = *(float4*)&acc[i][0];
      *(float4*)(rb + i * 8 + 4) = *(float4*)&acc[i][4];
    }
  }
  __syncthreads();
  if (oct < 4) {
    const float* rb = &rbuf[(oct * 32 + jt) * 33];
#pragma unroll
    for (int i = 0; i < 4; i++)
#pragma unroll
      for (int j = 0; j < 8; j++) acc[i][j] += rb[i * 8 + j];
  }
  __syncthreads();
  if (oct == 2 || oct == 3) {
    float* rb = &rbuf[((oct - 2) * 32 + jt) * 33];
#pragma unroll
    for (int i = 0; i < 4; i++) {
      *(float4*)(rb + i * 8)     = *(float4*)&acc[i][0];
      *(float4*)(rb + i * 8 + 4) = *(float4*)&acc[i][4];
    }
  }
  __syncthreads();
  if (oct < 2) {
    const float* rb = &rbuf[(oct * 32 + jt) * 33];
#pragma unroll
    for (int i = 0; i < 4; i++)
#pragma unroll
      for (int j = 0; j < 8; j++) acc[i][j] += rb[i * 8 + j];
  }
  __syncthreads();
  if (oct == 1) {
    float* rb = &rbuf[jt * 33];
#pragma unroll
    for (int i = 0; i < 4; i++) {
      *(float4*)(rb + i * 8)     = *(float4*)&acc[i][0];
      *(float4*)(rb + i * 8 + 4) = *(float4*)&acc[i][4];
    }
  }
  __syncthreads();
  if (oct == 0) {
    const float* rb = &rbuf[jt * 33];
    float4 bi = *(const float4*)(b1 + (size_t)e * H + j0);
    float bv[4] = {bi.x, bi.y, bi.z, bi.w};
    float* op = hT + ((size_t)e * H + j0) * B;
#pragma unroll
    for (int i = 0; i < 4; i++) {
      float o[8];
#pragma unroll
      for (int j = 0; j < 8; j++) {
        float v = acc[i][j] + rb[i * 8 + j] + bv[i];
        o[j] = 0.5f * v * (1.0f + erff(v * 0.70710678118654752f));
      }
      *(float4*)(op + i * 8)     = *(float4*)&o[0];
      *(float4*)(op + i * 8 + 4) = *(float4*)&o[4];
    }
  }
}

// ---- K7: gemm2 slab partial -> bf16 ys_part. grid E*16=1024 ----
__global__ __launch_bounds__(256) void k_gemm2(const float* __restrict__ w2,
                                               const float* __restrict__ hT,
                                               unsigned short* __restrict__ ys_part) {
  int blk = blockIdx.x;
  int ks = blk & 15, e = blk >> 4;
  int t = threadIdx.x;
  __shared__ float hsm[128 * 8];
  __shared__ float rbuf[128 * 32];
  ((float4*)hsm)[t] = ((const float4*)(hT + ((size_t)e * H + ks * 128) * B))[t];
  __syncthreads();
  int kk = t >> 7, dq = t & 127;
  int d0 = dq * 4;
  const float* wp = w2 + ((size_t)e * H + ks * 128 + kk * 64) * D + d0;
  const float* hb = hsm + kk * 64 * 8;
  float acc[4][8];
#pragma unroll
  for (int i = 0; i < 4; i++)
#pragma unroll
    for (int j = 0; j < 8; j++) acc[i][j] = 0.f;
#pragma unroll 8
  for (int k = 0; k < 64; k++) {
    float4 w = *(const float4*)(wp + (size_t)k * D);
    float h8[8];
    *(float4*)&h8[0] = *(float4*)&hb[k * 8];
    *(float4*)&h8[4] = *(float4*)&hb[k * 8 + 4];
#pragma unroll
    for (int bb = 0; bb < 8; bb++) {
      acc[0][bb] += w.x * h8[bb]; acc[1][bb] += w.y * h8[bb];
      acc[2][bb] += w.z * h8[bb]; acc[3][bb] += w.w * h8[bb];
    }
  }
  if (kk) {
#pragma unroll
    for (int i = 0; i < 4; i++) {
      *(float4*)&rbuf[dq * 32 + i * 8]     = *(float4*)&acc[i][0];
      *(float4*)&rbuf[dq * 32 + i * 8 + 4] = *(float4*)&acc[i][4];
    }
  }
  __syncthreads();
  if (!kk) {
    unsigned short* op = ys_part + (((size_t)ks * E + e) * D + d0) * B;
#pragma unroll
    for (int i = 0; i < 4; i++) {
      unsigned short us[8];
#pragma unroll
      for (int j = 0; j < 8; j++)
        us[j] = f2bf(acc[i][j] + rbuf[dq * 32 + i * 8 + j]);
      *(uint4*)(op + (size_t)i * 8) = *(uint4*)us;
    }
  }
}

// ---- K7b: ysT[b][d][e] = bf16(sum_ks ys_part + b2). grid E*4=256 ----
__global__ __launch_bounds__(256) void k_ysred(const unsigned short* __restrict__ ys_part,
                                               const float* __restrict__ b2,
                                               unsigned short* __restrict__ ysT) {
  int e = blockIdx.x >> 2, kq = blockIdx.x & 3;
  int t = threadIdx.x;
  int i4 = kq * 256 + t;  // ushort4 group within [512 d][8 b] slab
  float a[4] = {0.f, 0.f, 0.f, 0.f};
  for (int ks = 0; ks < NK2; ks++) {
    const unsigned short* q = ys_part + ((size_t)ks * E + e) * D * B;
    ushort4 v = *(const ushort4*)(q + (size_t)i4 * 4);
    a[0] += bf2f(v.x); a[1] += bf2f(v.y); a[2] += bf2f(v.z); a[3] += bf2f(v.w);
  }
  int d = i4 >> 1, bh = (i4 & 1) * 4;
  float bias = b2[e * D + d];
#pragma unroll
  for (int j = 0; j < 4; j++)
    ysT[((size_t)(bh + j) * D + d) * E + e] = f2bf(a[j] + bias);
}

// ---- K8: combine via MFMA: y[m][d] = sum_e c[m][e] * ysT[d][e].
// grid B*64*2=1024 (64-m tile, 256-d half), block 256 = 4 waves.
__global__ __launch_bounds__(256) void k_combine(const unsigned short* __restrict__ logitsb,
                                                 const unsigned short* __restrict__ ysT,
                                                 float* __restrict__ y) {
  __shared__ unsigned int yss[256 * 34];  // B^T: [d][e-pair], 34 w/row
  __shared__ unsigned int cb[64 * 34];    // A:   [m][e-pair], 34 w/row
  __shared__ float red[64][4];
  __shared__ float gmx[64], gsm[64];
  int t = threadIdx.x;
  int lane = t & 63, w = t >> 6;
  int blk = blockIdx.x;
  int dg = blk & 1, mb = (blk >> 1) & 63, b = blk >> 7;
  int m0 = mb * 64;
  // stage ysT half (straight copy; e-pairs already contiguous)
  {
    int dloc = t >> 3, ch = t & 7;
    const unsigned short* src = ysT + ((size_t)b * D + dg * 256) * E;
#pragma unroll
    for (int p = 0; p < 8; p++) {
      int d = p * 32 + dloc;
      const unsigned int* s = (const unsigned int*)&src[(size_t)d * E + ch * 8];
      unsigned int* dst = &yss[d * 34 + ch * 4];
      dst[0] = s[0]; dst[1] = s[1]; dst[2] = s[2]; dst[3] = s[3];
    }
  }
  // softmax over e for 64 rows
  int row = t >> 2, sub = t & 3;
  float r16[16];
  {
    const unsigned short* Lr = logitsb + ((size_t)(b * M + m0 + row)) * E + sub * 16;
    short8v l0 = *(const short8v*)Lr;
    short8v l1 = *(const short8v*)(Lr + 8);
#pragma unroll
    for (int k = 0; k < 8; k++) {
      r16[k]     = bf2f((unsigned short)l0[k]);
      r16[8 + k] = bf2f((unsigned short)l1[k]);
    }
  }
  float lm = -1e30f;
#pragma unroll
  for (int k = 0; k < 16; k++) lm = fmaxf(lm, r16[k]);
  red[row][sub] = lm;
  __syncthreads();
  if (sub == 0)
    gmx[row] = fmaxf(fmaxf(red[row][0], red[row][1]), fmaxf(red[row][2], red[row][3]));
  __syncthreads();
  float g = gmx[row];
  float ls = 0.f;
#pragma unroll
  for (int k = 0; k < 16; k++) {
    r16[k] = __expf(r16[k] - g);
    ls += r16[k];
  }
  red[row][sub] = ls;
  __syncthreads();
  if (sub == 0)
    gsm[row] = 1.0f / (red[row][0] + red[row][1] + red[row][2] + red[row][3]);
  __syncthreads();
  float is = gsm[row];
  {
    unsigned int us[8];
#pragma unroll
    for (int k = 0; k < 8; k++)
      us[k] = (unsigned int)f2bf(r16[2 * k] * is) |
              ((unsigned int)f2bf(r16[2 * k + 1] * is) << 16);
    unsigned int* dst = &cb[row * 34 + sub * 8];
#pragma unroll
    for (int k = 0; k < 8; k++) dst[k] = us[k];
  }
  __syncthreads();
  // MFMA: wave w covers d = w*64..w*64+63; K = 64 e in 2 steps
  int kg = lane >> 4, l15 = lane & 15;
  f32x4 acc[4][4];  // [mtile][dtile]
#pragma unroll
  for (int i = 0; i < 4; i++)
#pragma unroll
    for (int j = 0; j < 4; j++) acc[i][j] = (f32x4)(0.f);
#pragma unroll
  for (int ks = 0; ks < 2; ks++) {
    short8v afr[4];
#pragma unroll
    for (int mt = 0; mt < 4; mt++)
      afr[mt] = ld4w(cb, (mt * 16 + l15) * 34 + ks * 16 + kg * 4);
#pragma unroll
    for (int dt = 0; dt < 4; dt++) {
      short8v bfr = ld4w(yss, (w * 64 + dt * 16 + l15) * 34 + ks * 16 + kg * 4);
#pragma unroll
      for (int mt = 0; mt < 4; mt++)
        acc[mt][dt] = __builtin_amdgcn_mfma_f32_16x16x32_bf16(afr[mt], bfr, acc[mt][dt], 0, 0, 0);
    }
  }
  // write y
#pragma unroll
  for (int mt = 0; mt < 4; mt++)
#pragma unroll
    for (int dt = 0; dt < 4; dt++)
#pragma unroll
      for (int r = 0; r < 4; r++) {
        int m = mt * 16 + (lane >> 4) * 4 + r;
        int d = dg * 256 + w * 64 + dt * 16 + l15;
        y[((size_t)(b * M + m0 + m)) * D + d] = acc[mt][dt][r];
      }
}

extern "C" void kernel_launch(void* const* d_in, const int* in_sizes, int n_in,
                              void* d_out, int out_size, void* d_ws, size_t ws_size,
                              hipStream_t stream) {
  const float* x     = (const float*)d_in[0];
  const float* phi   = (const float*)d_in[1];
  const float* scale = (const float*)d_in[2];
  const float* w1    = (const float*)d_in[3];
  const float* b1    = (const float*)d_in[4];
  const float* w2    = (const float*)d_in[5];
  const float* b2    = (const float*)d_in[6];
  float* y = (float*)d_out;
  float* ws = (float*)d_ws;
  (void)in_sizes; (void)n_in; (void)out_size; (void)ws_size;

  float* invn             = ws + OFF_INVN;
  unsigned short* phT     = (unsigned short*)(ws + OFF_PHT);
  unsigned short* xnb     = (unsigned short*)(ws + OFF_XNB);
  unsigned short* logitsb = (unsigned short*)(ws + OFF_LOGB);
  float* pmax    = ws + OFF_PMAX;
  float* psum    = ws + OFF_PSUM;
  unsigned short* xs_part = (unsigned short*)(ws + OFF_XSP);
  float* xs_f    = ws + OFF_XSF;
  float* hT      = ws + OFF_HT;
  unsigned short* ys_part = (unsigned short*)(ws + OFF_YSP);
  unsigned short* ysT     = (unsigned short*)(ws + OFF_YST);

  k_phinorm<<<E, 256, 0, stream>>>(phi, scale, phT);
  k_logits<<<(B * M) / 128, 256, 0, stream>>>(x, phT, invn, xnb, logitsb, pmax, psum);
  k_dispatch<<<B * NSX * 2, 256, 0, stream>>>(xnb, logitsb, invn, pmax, xs_part);
  k_xsred<<<B * E, 256, 0, stream>>>(xs_part, pmax, psum, xs_f);
  k_gemm1g<<<E * 16, 256, 0, stream>>>(w1, b1, xs_f, hT);
  k_gemm2<<<E * NK2, 256, 0, stream>>>(w2, hT, ys_part);
  k_ysred<<<E * 4, 256, 0, stream>>>(ys_part, b2, ysT);
  k_combine<<<B * 64 * 2, 256, 0, stream>>>(logitsb, ysT, y);
}

// Round 7
// 198.702 us; speedup vs baseline: 1.9158x; 1.0179x over previous
//
#include <hip/hip_runtime.h>
#include <hip/hip_bf16.h>
#include <math.h>

// Soft-MoE forward. B=8, M=4096, D=512, E=64, P=1, H=2048.
// R7: (1) logits+dispatch fused (per-block-max partials, rescale in xsred);
//     (2) gemm1+gelu+gemm2 fused per (e, 128-j slab). 6 kernels total.

namespace {
constexpr int B = 8, M = 4096, D = 512, E = 64, H = 2048;
constexpr int NSD = 32;   // 128-row m-splits
constexpr int NK2 = 16;   // mlp j-slabs

constexpr size_t OFF_PHT  = 0;                                   // D*E bf16
constexpr size_t OFF_XNB  = OFF_PHT  + (size_t)D * E / 2;        // B*M*D bf16
constexpr size_t OFF_LOGB = OFF_XNB  + (size_t)B * M * D / 2;    // B*M*E bf16
constexpr size_t OFF_PMAX = OFF_LOGB + (size_t)B * M * E / 2;    // B*NSD*E f32
constexpr size_t OFF_PSUM = OFF_PMAX + (size_t)B * NSD * E;
constexpr size_t OFF_XSP  = OFF_PSUM + (size_t)B * NSD * E;      // NSD*B*E*D bf16
constexpr size_t OFF_XSF  = OFF_XSP  + (size_t)NSD * B * E * D / 2; // E*D*B f32
constexpr size_t OFF_YSP  = OFF_XSF  + (size_t)E * D * B;        // NK2*E*D*B bf16
constexpr size_t OFF_YST  = OFF_YSP  + (size_t)NK2 * E * D * B / 2; // B*D*E bf16
constexpr size_t WS_FLOATS = OFF_YST + (size_t)B * D * E / 2;    // ~65 MB
} // namespace

typedef __attribute__((ext_vector_type(8))) short short8v;
typedef __attribute__((ext_vector_type(4))) float f32x4;

static __device__ inline unsigned short f2bf(float f) {
  __hip_bfloat16 h = __float2bfloat16(f);
  return *reinterpret_cast<unsigned short*>(&h);
}
static __device__ inline float bf2f(unsigned short u) {
  unsigned int x = ((unsigned int)u) << 16;
  return __uint_as_float(x);
}
static __device__ inline short8v ld4w(const unsigned int* p, int a) {
  union { unsigned int u[4]; short8v v; } x;
  x.u[0] = p[a]; x.u[1] = p[a + 1]; x.u[2] = p[a + 2]; x.u[3] = p[a + 3];
  return x.v;
}

// ---- K1: phT[e][d] = bf16(scale * l2norm(phi, axis=0)). grid 64, block 256 ----
__global__ __launch_bounds__(256) void k_phinorm(const float* __restrict__ phi,
                                                 const float* __restrict__ scale,
                                                 unsigned short* __restrict__ phT) {
  int e = blockIdx.x;
  int t = threadIdx.x;
  float v0 = phi[(size_t)t * E + e];
  float v1 = phi[(size_t)(t + 256) * E + e];
  __shared__ float red[256];
  red[t] = v0 * v0 + v1 * v1;
  __syncthreads();
  for (int s = 128; s; s >>= 1) {
    if (t < s) red[t] += red[t + s];
    __syncthreads();
  }
  float inv = scale[0] / fmaxf(sqrtf(red[0]), 1e-12f);
  phT[(size_t)e * D + t]       = f2bf(v0 * inv);
  phT[(size_t)e * D + t + 256] = f2bf(v1 * inv);
}

// ---- K2: fused rownorm + logits MFMA + stats + dispatch MFMA ----
// grid 256 (b*32+ms, 128 rows each), block 256 = 4 waves.
// Outputs: xnb (bf16 x), logitsb, pmax/psum (block partials),
//          xs_part[ms][b][e][d] = sum_m exp(L - pmax_blk[e])*invn[m]*x[m][d] (bf16).
__global__ __launch_bounds__(256) void k_logdis(const float* __restrict__ x,
                                                const unsigned short* __restrict__ phT,
                                                unsigned short* __restrict__ xnb,
                                                unsigned short* __restrict__ logitsb,
                                                float* __restrict__ pmax,
                                                float* __restrict__ psum,
                                                unsigned short* __restrict__ xs_part) {
  __shared__ __align__(16) unsigned char pool[80896];
  // phase 1 aliases
  unsigned short* phs = (unsigned short*)pool;            // [64 e][520 k]
  unsigned short* xA  = (unsigned short*)(pool + 66560);  // [128 m][56 k]
  // phase 3 aliases
  unsigned int* weT = (unsigned int*)pool;                // [64 e][65 mp]
  unsigned int* xnT = (unsigned int*)(pool + 16640);      // [128 d][65 mp]
  unsigned short* rp = (unsigned short*)(pool + 49920);   // [64 e][136 d]
  __shared__ float invs[128];
  __shared__ float smax[4][64];
  __shared__ float bmax[64];
  int t = threadIdx.x;
  int lane = t & 63, w = t >> 6;
  int blk = blockIdx.x;
  int b = blk >> 5, ms = blk & 31;
  int rowbase = blk * 128;
  // stage phin bf16 [64][512]
  {
    int e = t >> 2, q0 = (t & 3) * 16;
#pragma unroll
    for (int q = 0; q < 16; q++)
      *(short8v*)&phs[e * 520 + (q0 + q) * 8] =
          *(const short8v*)&phT[(size_t)e * D + (q0 + q) * 8];
  }
  int srow = t >> 1;
  int kb = (t & 1) * 16;
  float ss = 0.f;
  f32x4 acc[2][4];
#pragma unroll
  for (int i = 0; i < 2; i++)
#pragma unroll
    for (int j = 0; j < 4; j++) acc[i][j] = (f32x4)(0.f);
  int kg = lane >> 4;
  int l15 = lane & 15;
  for (int ks = 0; ks < 16; ks++) {
    __syncthreads();
    const float4* xp = (const float4*)(x + (size_t)(rowbase + srow) * D + ks * 32 + kb);
#pragma unroll
    for (int q = 0; q < 4; q++) {
      float4 v = xp[q];
      ss += v.x * v.x + v.y * v.y + v.z * v.z + v.w * v.w;
      ushort4 u;
      u.x = f2bf(v.x); u.y = f2bf(v.y); u.z = f2bf(v.z); u.w = f2bf(v.w);
      *(ushort4*)&xA[srow * 56 + kb + q * 4] = u;
    }
    __syncthreads();
    {  // export bf16 x (consumed by phase 3 from L2)
      uint4 x0 = *(uint4*)&xA[srow * 56 + kb];
      uint4 x1 = *(uint4*)&xA[srow * 56 + kb + 8];
      size_t go = (size_t)(rowbase + srow) * D + ks * 32 + kb;
      *(uint4*)&xnb[go]     = x0;
      *(uint4*)&xnb[go + 8] = x1;
    }
    short8v a0 = *(short8v*)&xA[(w * 32 + l15) * 56 + kg * 8];
    short8v a1 = *(short8v*)&xA[(w * 32 + 16 + l15) * 56 + kg * 8];
    short8v b0 = *(short8v*)&phs[(l15)      * 520 + ks * 32 + kg * 8];
    short8v b1 = *(short8v*)&phs[(16 + l15) * 520 + ks * 32 + kg * 8];
    short8v b2 = *(short8v*)&phs[(32 + l15) * 520 + ks * 32 + kg * 8];
    short8v b3 = *(short8v*)&phs[(48 + l15) * 520 + ks * 32 + kg * 8];
    acc[0][0] = __builtin_amdgcn_mfma_f32_16x16x32_bf16(a0, b0, acc[0][0], 0, 0, 0);
    acc[0][1] = __builtin_amdgcn_mfma_f32_16x16x32_bf16(a0, b1, acc[0][1], 0, 0, 0);
    acc[0][2] = __builtin_amdgcn_mfma_f32_16x16x32_bf16(a0, b2, acc[0][2], 0, 0, 0);
    acc[0][3] = __builtin_amdgcn_mfma_f32_16x16x32_bf16(a0, b3, acc[0][3], 0, 0, 0);
    acc[1][0] = __builtin_amdgcn_mfma_f32_16x16x32_bf16(a1, b0, acc[1][0], 0, 0, 0);
    acc[1][1] = __builtin_amdgcn_mfma_f32_16x16x32_bf16(a1, b1, acc[1][1], 0, 0, 0);
    acc[1][2] = __builtin_amdgcn_mfma_f32_16x16x32_bf16(a1, b2, acc[1][2], 0, 0, 0);
    acc[1][3] = __builtin_amdgcn_mfma_f32_16x16x32_bf16(a1, b3, acc[1][3], 0, 0, 0);
  }
  ss += __shfl_xor(ss, 1, 64);
  float iv = 1.0f / fmaxf(sqrtf(ss), 1e-12f);
  if ((t & 1) == 0) invs[srow] = iv;
  __syncthreads();  // pool (phs/xA) now dead; invs visible
  int rsub = kg * 4;
  float lm[4] = {-1e30f, -1e30f, -1e30f, -1e30f};
#pragma unroll
  for (int fi = 0; fi < 2; fi++)
#pragma unroll
    for (int r = 0; r < 4; r++) {
      int row = w * 32 + fi * 16 + rsub + r;
      float ivr = invs[row];
#pragma unroll
      for (int eg = 0; eg < 4; eg++) {
        float v = acc[fi][eg][r] * ivr;
        logitsb[(size_t)(rowbase + row) * E + eg * 16 + l15] = f2bf(v);
        lm[eg] = fmaxf(lm[eg], v);
      }
    }
#pragma unroll
  for (int eg = 0; eg < 4; eg++) {
    lm[eg] = fmaxf(lm[eg], __shfl_xor(lm[eg], 16, 64));
    lm[eg] = fmaxf(lm[eg], __shfl_xor(lm[eg], 32, 64));
  }
  if (lane < 16)
#pragma unroll
    for (int eg = 0; eg < 4; eg++) smax[w][eg * 16 + lane] = lm[eg];
  __syncthreads();
  if (t < 64)
    bmax[t] = fmaxf(fmaxf(smax[0][t], smax[1][t]), fmaxf(smax[2][t], smax[3][t]));
  __syncthreads();
  // psum pass + dispatch weights weT[e][mp] = pack(exp(L-bmax)*invn for m pair)
  float ps[4] = {0.f, 0.f, 0.f, 0.f};
#pragma unroll
  for (int fi = 0; fi < 2; fi++)
#pragma unroll
    for (int r2 = 0; r2 < 2; r2++) {
      int rowA = w * 32 + fi * 16 + rsub + 2 * r2;
      float iv0 = invs[rowA], iv1 = invs[rowA + 1];
#pragma unroll
      for (int eg = 0; eg < 4; eg++) {
        float bm = bmax[eg * 16 + l15];
        float p0 = __expf(acc[fi][eg][2 * r2]     * iv0 - bm);
        float p1 = __expf(acc[fi][eg][2 * r2 + 1] * iv1 - bm);
        ps[eg] += p0 + p1;
        weT[(eg * 16 + l15) * 65 + (w * 16 + fi * 8 + (rsub >> 1) + r2)] =
            (unsigned int)f2bf(p0 * iv0) | ((unsigned int)f2bf(p1 * iv1) << 16);
      }
    }
#pragma unroll
  for (int eg = 0; eg < 4; eg++) {
    ps[eg] += __shfl_xor(ps[eg], 16, 64);
    ps[eg] += __shfl_xor(ps[eg], 32, 64);
  }
  __syncthreads();
  if (lane < 16)
#pragma unroll
    for (int eg = 0; eg < 4; eg++) smax[w][eg * 16 + lane] = ps[eg];
  __syncthreads();
  if (t < 64) {
    pmax[(size_t)blk * 64 + t] = bmax[t];
    psum[(size_t)blk * 64 + t] =
        smax[0][t] + smax[1][t] + smax[2][t] + smax[3][t];
  }
  // ---- phase 3: xs_part = weT(64e x 128m) @ xn(128m x 512d), 4 d-chunks ----
  unsigned short* outp = xs_part + ((size_t)ms * B + b) * E * D;
  for (int dc = 0; dc < 4; dc++) {
    __syncthreads();  // weT ready (dc=0); prior chunk rp/xnT reads done
    // stage xnT [128 d][mp] from xnb (L2-hot), transposing with m-pair packing
#pragma unroll
    for (int i = 0; i < 16; i++) {
      int flat = i * 256 + t;
      int mp = flat >> 6, d2 = flat & 63;
      size_t rbase = (size_t)(rowbase + 2 * mp) * D + dc * 128 + d2 * 2;
      unsigned int ua = *(const unsigned int*)&xnb[rbase];
      unsigned int ub = *(const unsigned int*)&xnb[rbase + D];
      xnT[(2 * d2 + 0) * 65 + mp] = (ua & 0xffffu) | ((ub & 0xffffu) << 16);
      xnT[(2 * d2 + 1) * 65 + mp] = (ua >> 16) | (ub & 0xffff0000u);
    }
    __syncthreads();
    f32x4 ac3[4][2];
#pragma unroll
    for (int i = 0; i < 4; i++) { ac3[i][0] = (f32x4)(0.f); ac3[i][1] = (f32x4)(0.f); }
#pragma unroll
    for (int ks2 = 0; ks2 < 4; ks2++) {
      short8v afr[4];
#pragma unroll
      for (int et = 0; et < 4; et++)
        afr[et] = ld4w(weT, (et * 16 + l15) * 65 + ks2 * 16 + kg * 4);
#pragma unroll
      for (int dtl = 0; dtl < 2; dtl++) {
        short8v bfr = ld4w(xnT, (w * 32 + dtl * 16 + l15) * 65 + ks2 * 16 + kg * 4);
#pragma unroll
        for (int et = 0; et < 4; et++)
          ac3[et][dtl] = __builtin_amdgcn_mfma_f32_16x16x32_bf16(afr[et], bfr, ac3[et][dtl], 0, 0, 0);
      }
    }
    // repack to rp [64 e][136 d-chunk]
#pragma unroll
    for (int et = 0; et < 4; et++)
#pragma unroll
      for (int dtl = 0; dtl < 2; dtl++)
#pragma unroll
        for (int r = 0; r < 4; r++) {
          int e = et * 16 + rsub + r;
          int d = w * 32 + dtl * 16 + l15;
          rp[e * 136 + d] = f2bf(ac3[et][dtl][r]);
        }
    __syncthreads();
    // coalesced store [64 e][128 d] chunk
    {
      int g = t >> 4, dch = t & 15;
#pragma unroll
      for (int pp = 0; pp < 4; pp++) {
        int el = pp * 16 + g;
        uint4 v = *(uint4*)&rp[el * 136 + dch * 8];
        *(uint4*)(outp + (size_t)el * D + dc * 128 + dch * 8) = v;
      }
    }
  }
}

// ---- K3: xs_f[e][d][b] = (sum_ms xs_part * exp(pmax-gm)) / dsum. grid B*E=512 ----
__global__ __launch_bounds__(256) void k_xsred(const unsigned short* __restrict__ xs_part,
                                               const float* __restrict__ pmax,
                                               const float* __restrict__ psum,
                                               float* __restrict__ xs_f) {
  int blk = blockIdx.x;
  int b = blk >> 6, e = blk & 63;
  int t = threadIdx.x;
  float gm = -1e30f;
  for (int s = 0; s < NSD; s++)
    gm = fmaxf(gm, pmax[((size_t)(b * NSD + s)) * 64 + e]);
  float gs = 0.f;
  for (int s = 0; s < NSD; s++)
    gs += psum[((size_t)(b * NSD + s)) * 64 + e] *
          __expf(pmax[((size_t)(b * NSD + s)) * 64 + e] - gm);
  float inv = 1.0f / gs;
  size_t base = (((size_t)b * E + e) * D) / 2 + t;
  size_t slab = ((size_t)B * E * D) / 2;
  float a0 = 0.f, a1 = 0.f;
  const unsigned int* pp = (const unsigned int*)xs_part;
  for (int s = 0; s < NSD; s++) {
    float f = __expf(pmax[((size_t)(b * NSD + s)) * 64 + e] - gm);
    unsigned int v = pp[(size_t)s * slab + base];
    a0 += f * bf2f((unsigned short)(v & 0xffff));
    a1 += f * bf2f((unsigned short)(v >> 16));
  }
  int d = t * 2;
  xs_f[((size_t)e * D + d) * B + b]     = a0 * inv;
  xs_f[((size_t)e * D + d + 1) * B + b] = a1 * inv;
}

// ---- K4: fused MLP: block (e, s) -> h slab [128 j][8 b] -> gelu -> gemm2 partial.
// grid E*16=1024, block 256.
__global__ __launch_bounds__(256) void k_mlp(const float* __restrict__ w1,
                                             const float* __restrict__ b1,
                                             const float* __restrict__ w2,
                                             const float* __restrict__ xs_f,
                                             unsigned short* __restrict__ ys_part) {
  __shared__ float xsm[512 * 8];     // 16 KB
  __shared__ float rbuf[4224];       // 16.9 KB (gemm1 reduce / gemm2 combine)
  __shared__ float hsm[128 * 8];     // 4 KB
  int blk = blockIdx.x;
  int e = blk >> 4, s = blk & 15;
  int t = threadIdx.x;
  const float4* xsrc = (const float4*)(xs_f + (size_t)e * D * B);
#pragma unroll
  for (int k = 0; k < 4; k++) ((float4*)xsm)[t + 256 * k] = xsrc[t + 256 * k];
  __syncthreads();
  // --- gemm1: 8 d-octants x (32 thr x 4 j x 8 b) ---
  int oct = t >> 5, jt = t & 31;
  int j0 = s * 128 + jt * 4;
  {
    const float* wp = w1 + ((size_t)e * D + oct * 64) * H + j0;
    const float* xb = xsm + oct * 64 * 8;
    float acc[4][8];
#pragma unroll
    for (int i = 0; i < 4; i++)
#pragma unroll
      for (int j = 0; j < 8; j++) acc[i][j] = 0.f;
#pragma unroll 8
    for (int d = 0; d < 64; d++) {
      float4 w = *(const float4*)(wp + (size_t)d * H);
      float x8[8];
      *(float4*)&x8[0] = *(float4*)&xb[d * 8];
      *(float4*)&x8[4] = *(float4*)&xb[d * 8 + 4];
#pragma unroll
      for (int bb = 0; bb < 8; bb++) {
        acc[0][bb] += w.x * x8[bb]; acc[1][bb] += w.y * x8[bb];
        acc[2][bb] += w.z * x8[bb]; acc[3][bb] += w.w * x8[bb];
      }
    }
    if (oct >= 4) {
      float* rb = &rbuf[((oct - 4) * 32 + jt) * 33];
#pragma unroll
      for (int i = 0; i < 4; i++) {
        *(float4*)(rb + i * 8)     = *(float4*)&acc[i][0];
        *(float4*)(rb + i * 8 + 4) = *(float4*)&acc[i][4];
      }
    }
    __syncthreads();
    if (oct < 4) {
      const float* rb = &rbuf[(oct * 32 + jt) * 33];
#pragma unroll
      for (int i = 0; i < 4; i++)
#pragma unroll
        for (int j = 0; j < 8; j++) acc[i][j] += rb[i * 8 + j];
    }
    __syncthreads();
    if (oct == 2 || oct == 3) {
      float* rb = &rbuf[((oct - 2) * 32 + jt) * 33];
#pragma unroll
      for (int i = 0; i < 4; i++) {
        *(float4*)(rb + i * 8)     = *(float4*)&acc[i][0];
        *(float4*)(rb + i * 8 + 4) = *(float4*)&acc[i][4];
      }
    }
    __syncthreads();
    if (oct < 2) {
      const float* rb = &rbuf[(oct * 32 + jt) * 33];
#pragma unroll
      for (int i = 0; i < 4; i++)
#pragma unroll
        for (int j = 0; j < 8; j++) acc[i][j] += rb[i * 8 + j];
    }
    __syncthreads();
    if (oct == 1) {
      float* rb = &rbuf[jt * 33];
#pragma unroll
      for (int i = 0; i < 4; i++) {
        *(float4*)(rb + i * 8)     = *(float4*)&acc[i][0];
        *(float4*)(rb + i * 8 + 4) = *(float4*)&acc[i][4];
      }
    }
    __syncthreads();
    if (oct == 0) {
      const float* rb = &rbuf[jt * 33];
      float4 bi = *(const float4*)(b1 + (size_t)e * H + j0);
      float bv[4] = {bi.x, bi.y, bi.z, bi.w};
#pragma unroll
      for (int i = 0; i < 4; i++)
#pragma unroll
        for (int j = 0; j < 8; j++) {
          float v = acc[i][j] + rb[i * 8 + j] + bv[i];
          hsm[(jt * 4 + i) * 8 + j] = 0.5f * v * (1.0f + erff(v * 0.70710678118654752f));
        }
    }
  }
  __syncthreads();  // hsm ready; rbuf free for gemm2 combine
  // --- gemm2 partial over this 128-j slab ---
  {
    int kk = t >> 7, dq = t & 127;
    int d0 = dq * 4;
    const float* wp = w2 + ((size_t)e * H + s * 128 + kk * 64) * D + d0;
    const float* hb = hsm + kk * 64 * 8;
    float acc[4][8];
#pragma unroll
    for (int i = 0; i < 4; i++)
#pragma unroll
      for (int j = 0; j < 8; j++) acc[i][j] = 0.f;
#pragma unroll 8
    for (int k = 0; k < 64; k++) {
      float4 w = *(const float4*)(wp + (size_t)k * D);
      float h8[8];
      *(float4*)&h8[0] = *(float4*)&hb[k * 8];
      *(float4*)&h8[4] = *(float4*)&hb[k * 8 + 4];
#pragma unroll
      for (int bb = 0; bb < 8; bb++) {
        acc[0][bb] += w.x * h8[bb]; acc[1][bb] += w.y * h8[bb];
        acc[2][bb] += w.z * h8[bb]; acc[3][bb] += w.w * h8[bb];
      }
    }
    if (kk) {
#pragma unroll
      for (int i = 0; i < 4; i++) {
        *(float4*)&rbuf[dq * 32 + i * 8]     = *(float4*)&acc[i][0];
        *(float4*)&rbuf[dq * 32 + i * 8 + 4] = *(float4*)&acc[i][4];
      }
    }
    __syncthreads();
    if (!kk) {
      unsigned short* op = ys_part + (((size_t)s * E + e) * D + d0) * B;
#pragma unroll
      for (int i = 0; i < 4; i++) {
        unsigned short us[8];
#pragma unroll
        for (int j = 0; j < 8; j++)
          us[j] = f2bf(acc[i][j] + rbuf[dq * 32 + i * 8 + j]);
        *(uint4*)(op + (size_t)i * 8) = *(uint4*)us;
      }
    }
  }
}

// ---- K5: ysT[b][d][e] = bf16(sum_s ys_part + b2). grid E*4=256 ----
__global__ __launch_bounds__(256) void k_ysred(const unsigned short* __restrict__ ys_part,
                                               const float* __restrict__ b2,
                                               unsigned short* __restrict__ ysT) {
  int e = blockIdx.x >> 2, kq = blockIdx.x & 3;
  int t = threadIdx.x;
  int i4 = kq * 256 + t;
  float a[4] = {0.f, 0.f, 0.f, 0.f};
  for (int ks = 0; ks < NK2; ks++) {
    const unsigned short* q = ys_part + ((size_t)ks * E + e) * D * B;
    ushort4 v = *(const ushort4*)(q + (size_t)i4 * 4);
    a[0] += bf2f(v.x); a[1] += bf2f(v.y); a[2] += bf2f(v.z); a[3] += bf2f(v.w);
  }
  int d = i4 >> 1, bh = (i4 & 1) * 4;
  float bias = b2[e * D + d];
#pragma unroll
  for (int j = 0; j < 4; j++)
    ysT[((size_t)(bh + j) * D + d) * E + e] = f2bf(a[j] + bias);
}

// ---- K6: combine via MFMA. grid B*64*2=1024, block 256 = 4 waves ----
__global__ __launch_bounds__(256) void k_combine(const unsigned short* __restrict__ logitsb,
                                                 const unsigned short* __restrict__ ysT,
                                                 float* __restrict__ y) {
  __shared__ unsigned int yss[256 * 34];
  __shared__ unsigned int cb[64 * 34];
  __shared__ float red[64][4];
  __shared__ float gmx[64], gsm[64];
  int t = threadIdx.x;
  int lane = t & 63, w = t >> 6;
  int blk = blockIdx.x;
  int dg = blk & 1, mb = (blk >> 1) & 63, b = blk >> 7;
  int m0 = mb * 64;
  {
    int dloc = t >> 3, ch = t & 7;
    const unsigned short* src = ysT + ((size_t)b * D + dg * 256) * E;
#pragma unroll
    for (int p = 0; p < 8; p++) {
      int d = p * 32 + dloc;
      const unsigned int* sp = (const unsigned int*)&src[(size_t)d * E + ch * 8];
      unsigned int* dst = &yss[d * 34 + ch * 4];
      dst[0] = sp[0]; dst[1] = sp[1]; dst[2] = sp[2]; dst[3] = sp[3];
    }
  }
  int row = t >> 2, sub = t & 3;
  float r16[16];
  {
    const unsigned short* Lr = logitsb + ((size_t)(b * M + m0 + row)) * E + sub * 16;
    short8v l0 = *(const short8v*)Lr;
    short8v l1 = *(const short8v*)(Lr + 8);
#pragma unroll
    for (int k = 0; k < 8; k++) {
      r16[k]     = bf2f((unsigned short)l0[k]);
      r16[8 + k] = bf2f((unsigned short)l1[k]);
    }
  }
  float lm = -1e30f;
#pragma unroll
  for (int k = 0; k < 16; k++) lm = fmaxf(lm, r16[k]);
  red[row][sub] = lm;
  __syncthreads();
  if (sub == 0)
    gmx[row] = fmaxf(fmaxf(red[row][0], red[row][1]), fmaxf(red[row][2], red[row][3]));
  __syncthreads();
  float g = gmx[row];
  float ls = 0.f;
#pragma unroll
  for (int k = 0; k < 16; k++) {
    r16[k] = __expf(r16[k] - g);
    ls += r16[k];
  }
  red[row][sub] = ls;
  __syncthreads();
  if (sub == 0)
    gsm[row] = 1.0f / (red[row][0] + red[row][1] + red[row][2] + red[row][3]);
  __syncthreads();
  float is = gsm[row];
  {
    unsigned int us[8];
#pragma unroll
    for (int k = 0; k < 8; k++)
      us[k] = (unsigned int)f2bf(r16[2 * k] * is) |
              ((unsigned int)f2bf(r16[2 * k + 1] * is) << 16);
    unsigned int* dst = &cb[row * 34 + sub * 8];
#pragma unroll
    for (int k = 0; k < 8; k++) dst[k] = us[k];
  }
  __syncthreads();
  int kg = lane >> 4, l15 = lane & 15;
  f32x4 acc[4][4];
#pragma unroll
  for (int i = 0; i < 4; i++)
#pragma unroll
    for (int j = 0; j < 4; j++) acc[i][j] = (f32x4)(0.f);
#pragma unroll
  for (int ks = 0; ks < 2; ks++) {
    short8v afr[4];
#pragma unroll
    for (int mt = 0; mt < 4; mt++)
      afr[mt] = ld4w(cb, (mt * 16 + l15) * 34 + ks * 16 + kg * 4);
#pragma unroll
    for (int dt = 0; dt < 4; dt++) {
      short8v bfr = ld4w(yss, (w * 64 + dt * 16 + l15) * 34 + ks * 16 + kg * 4);
#pragma unroll
      for (int mt = 0; mt < 4; mt++)
        acc[mt][dt] = __builtin_amdgcn_mfma_f32_16x16x32_bf16(afr[mt], bfr, acc[mt][dt], 0, 0, 0);
    }
  }
#pragma unroll
  for (int mt = 0; mt < 4; mt++)
#pragma unroll
    for (int dt = 0; dt < 4; dt++)
#pragma unroll
      for (int r = 0; r < 4; r++) {
        int m = mt * 16 + kg * 4 + r;
        int d = dg * 256 + w * 64 + dt * 16 + l15;
        y[((size_t)(b * M + m0 + m)) * D + d] = acc[mt][dt][r];
      }
}

extern "C" void kernel_launch(void* const* d_in, const int* in_sizes, int n_in,
                              void* d_out, int out_size, void* d_ws, size_t ws_size,
                              hipStream_t stream) {
  const float* x     = (const float*)d_in[0];
  const float* phi   = (const float*)d_in[1];
  const float* scale = (const float*)d_in[2];
  const float* w1    = (const float*)d_in[3];
  const float* b1    = (const float*)d_in[4];
  const float* w2    = (const float*)d_in[5];
  const float* b2    = (const float*)d_in[6];
  float* y = (float*)d_out;
  float* ws = (float*)d_ws;
  (void)in_sizes; (void)n_in; (void)out_size; (void)ws_size;

  unsigned short* phT     = (unsigned short*)(ws + OFF_PHT);
  unsigned short* xnb     = (unsigned short*)(ws + OFF_XNB);
  unsigned short* logitsb = (unsigned short*)(ws + OFF_LOGB);
  float* pmax    = ws + OFF_PMAX;
  float* psum    = ws + OFF_PSUM;
  unsigned short* xs_part = (unsigned short*)(ws + OFF_XSP);
  float* xs_f    = ws + OFF_XSF;
  unsigned short* ys_part = (unsigned short*)(ws + OFF_YSP);
  unsigned short* ysT     = (unsigned short*)(ws + OFF_YST);

  k_phinorm<<<E, 256, 0, stream>>>(phi, scale, phT);
  k_logdis<<<B * NSD, 256, 0, stream>>>(x, phT, xnb, logitsb, pmax, psum, xs_part);
  k_xsred<<<B * E, 256, 0, stream>>>(xs_part, pmax, psum, xs_f);
  k_mlp<<<E * 16, 256, 0, stream>>>(w1, b1, w2, xs_f, ys_part);
  k_ysred<<<E * 4, 256, 0, stream>>>(ys_part, b2, ysT);
  k_combine<<<B * 64 * 2, 256, 0, stream>>>(logitsb, ysT, y);
}